// Round 11
// baseline (659.171 us; speedup 1.0000x reference)
//
#include <hip/hip_runtime.h>
#include <hip/hip_bf16.h>

#define N_NODES 100000
#define N_EDGES 1600000
#define NB ((N_NODES + 255) / 256)          // 391 dst-buckets of 256 nodes
#define CHUNK 16384
#define NBLK ((N_EDGES + CHUNK - 1) / CHUNK) // 98 partition blocks
#define NSHADOW 64

typedef short sh8 __attribute__((ext_vector_type(8)));
typedef float f32x4 __attribute__((ext_vector_type(4)));

__device__ __forceinline__ float bf2f(unsigned short s) {
    return __uint_as_float(((unsigned int)s) << 16);
}
__device__ __forceinline__ unsigned short f2bf(float f) {
    unsigned int u = __float_as_uint(f);
    unsigned int r = (u + 0x7FFFu + ((u >> 16) & 1u)) >> 16;
    return (unsigned short)r;
}
__device__ __forceinline__ float blo(unsigned int u) { return __uint_as_float(u << 16); }
__device__ __forceinline__ float bhi(unsigned int u) { return __uint_as_float(u & 0xffff0000u); }

// ---------------- graph preprocessing: partition + bucket sort -> CSR ----------------

__global__ __launch_bounds__(256) void k_hist(const int* __restrict__ ei, int* __restrict__ histG) {
    __shared__ int hist[NB];
    int blk = blockIdx.x, t = threadIdx.x;
    for (int b = t; b < NB; b += 256) hist[b] = 0;
    __syncthreads();
    int e0 = blk * CHUNK;
    int e1 = min(e0 + CHUNK, N_EDGES);
    for (int e = e0 + t; e < e1; e += 256) atomicAdd(&hist[ei[N_EDGES + e] >> 8], 1);
    __syncthreads();
    for (int b = t; b < NB; b += 256) histG[b * NBLK + blk] = hist[b];
}

__global__ __launch_bounds__(128) void k_scanrow(int* __restrict__ histG, int* __restrict__ rowsum) {
    __shared__ int sm[128];
    int b = blockIdx.x, t = threadIdx.x;
    int v = (t < NBLK) ? histG[b * NBLK + t] : 0;
    sm[t] = v; __syncthreads();
    for (int d = 1; d < 128; d <<= 1) {
        int add = (t >= d) ? sm[t - d] : 0;
        __syncthreads(); sm[t] += add; __syncthreads();
    }
    if (t < NBLK) histG[b * NBLK + t] = sm[t] - v;
    if (t == 127) rowsum[b] = sm[127];
}

__global__ __launch_bounds__(512) void k_scanbkt(const int* __restrict__ rowsum, int* __restrict__ rowbase) {
    __shared__ int sm[512];
    int t = threadIdx.x;
    int v = (t < NB) ? rowsum[t] : 0;
    sm[t] = v; __syncthreads();
    for (int d = 1; d < 512; d <<= 1) {
        int add = (t >= d) ? sm[t - d] : 0;
        __syncthreads(); sm[t] += add; __syncthreads();
    }
    if (t <= NB) rowbase[t] = sm[t] - v;
}

__global__ __launch_bounds__(256) void k_part(const int* __restrict__ ei, const int* __restrict__ histG,
                                              const int* __restrict__ rowbase, unsigned* __restrict__ pairs) {
    __shared__ int cur[NB];
    int blk = blockIdx.x, t = threadIdx.x;
    for (int b = t; b < NB; b += 256) cur[b] = rowbase[b] + histG[b * NBLK + blk];
    __syncthreads();
    int e0 = blk * CHUNK;
    int e1 = min(e0 + CHUNK, N_EDGES);
    for (int e = e0 + t; e < e1; e += 256) {
        int s = ei[e], d = ei[N_EDGES + e];
        int pos = atomicAdd(&cur[d >> 8], 1);
        pairs[pos] = ((unsigned)s << 8) | (unsigned)(d & 255);
    }
}

__global__ __launch_bounds__(256) void k_bsort(const unsigned* __restrict__ pairs, const int* __restrict__ rowbase,
                                               int* __restrict__ col, int* __restrict__ basep,
                                               int* __restrict__ deg, float* __restrict__ dinv,
                                               float* __restrict__ sdeg) {
    __shared__ int cnt[256];
    __shared__ int sm[256];
    __shared__ int cur[256];
    int b = blockIdx.x, t = threadIdx.x;
    int base = rowbase[b], end = rowbase[b + 1];
    cnt[t] = 0; __syncthreads();
    for (int e = base + t; e < end; e += 256) atomicAdd(&cnt[pairs[e] & 255], 1);
    __syncthreads();
    int v = cnt[t];
    sm[t] = v; __syncthreads();
    for (int d = 1; d < 256; d <<= 1) {
        int add = (t >= d) ? sm[t - d] : 0;
        __syncthreads(); sm[t] += add; __syncthreads();
    }
    int excl = sm[t] - v;
    cur[t] = excl;
    int gd = (b << 8) + t;
    if (gd < N_NODES) {
        basep[gd] = base + excl;
        deg[gd] = v;
        dinv[gd] = rsqrtf((float)(v + 1));
        sdeg[gd] = sqrtf((float)(v + 1));
    }
    __syncthreads();
    for (int e = base + t; e < end; e += 256) {
        unsigned p = pairs[e];
        int pos = atomicAdd(&cur[p & 255], 1);
        col[base + pos] = (int)(p >> 8);
    }
}

// svec[w] = dinv[w]*(sum_e dinv[src] + dinv[w])
__global__ __launch_bounds__(256) void k_svec(const int* __restrict__ col, const int* __restrict__ basep,
                                              const int* __restrict__ deg, const float* __restrict__ dinv,
                                              float* __restrict__ svec) {
    int w = (blockIdx.x * 256 + threadIdx.x) >> 6;
    if (w >= N_NODES) return;
    int lane = threadIdx.x & 63;
    int start = basep[w], cnt = deg[w];
    float s = 0.f;
    for (int j = lane; j < cnt; j += 64) s += dinv[col[start + j]];
#pragma unroll
    for (int off = 32; off; off >>= 1) s += __shfl_down(s, off, 64);
    if (lane == 0) { float di = dinv[w]; svec[w] = di * (s + di); }
}

// ---------------- all W transpose + bf16 convert in one dispatch ----------------

__global__ void k_wconv_all(const float* __restrict__ W1, const float* __restrict__ W2,
                            const float* __restrict__ W3, const float* __restrict__ W4,
                            unsigned short* __restrict__ Wt1, unsigned short* __restrict__ Wt2,
                            unsigned short* __restrict__ Wt3, unsigned short* __restrict__ Wt4) {
    int idx = blockIdx.x * 256 + threadIdx.x;
    const float* W; unsigned short* Wt; int K, N, base;
    if (idx < 32768)       { W = W1; Wt = Wt1; K = 256; N = 128; base = 0; }
    else if (idx < 65536)  { W = W2; Wt = Wt2; K = 128; N = 256; base = 32768; }
    else if (idx < 98304)  { W = W3; Wt = Wt3; K = 256; N = 128; base = 65536; }
    else if (idx < 106496) { W = W4; Wt = Wt4; K = 128; N = 64;  base = 98304; }
    else return;
    int li = idx - base;
    int n = li / K, k = li - n * K;
    Wt[li] = f2bf(W[(size_t)k * N + n]);
}

// ---------------- shadow reduce: dst[f] = sum_s shadow[s][f]; shadow cleared ----------------

__global__ __launch_bounds__(256) void k_bnred(float* __restrict__ shadow, float* __restrict__ dst) {
    int f = blockIdx.x * 256 + threadIdx.x; // 0..511
    float s = 0.f;
#pragma unroll
    for (int i = 0; i < NSHADOW; ++i) {
        s += shadow[i * 512 + f];
        shadow[i * 512 + f] = 0.f;
    }
    dst[f] = s;
}

// ---------------- vectorized BN stats pass: shadow += per-feature {sum, sumsq} ----------------

template <int D, bool INF32, bool RESCALE>
__global__ __launch_bounds__(256) void k_bnstats(const void* __restrict__ h,
                                                 const float* __restrict__ sdeg,
                                                 float* __restrict__ shadow) {
    constexpr int VEC = INF32 ? 4 : 8;
    constexpr int TPR = D / VEC;           // threads per row
    constexpr int RPB = 256 / TPR;         // rows in flight per block
    const int tid = threadIdx.x;
    const int rg = tid / TPR;
    const int oc = tid % TPR;
    const int fb = oc * VEC;

    float s1[VEC], s2[VEC];
#pragma unroll
    for (int k = 0; k < VEC; ++k) { s1[k] = 0.f; s2[k] = 0.f; }

    for (int r = blockIdx.x * RPB + rg; r < N_NODES; r += gridDim.x * RPB) {
        float rs = 1.f;
        if constexpr (RESCALE) rs = sdeg[r];
        if constexpr (INF32) {
            float4 v = *(const float4*)((const float*)h + (size_t)r * D + fb);
            float vv[4] = {v.x, v.y, v.z, v.w};
#pragma unroll
            for (int k = 0; k < 4; ++k) {
                float val = vv[k];
                if constexpr (RESCALE) val *= rs;
                s1[k] += val; s2[k] += val * val;
            }
        } else {
            uint4 u = *(const uint4*)((const unsigned short*)h + (size_t)r * D + fb);
            unsigned uu[4] = {u.x, u.y, u.z, u.w};
#pragma unroll
            for (int k = 0; k < 4; ++k) {
                float v0 = blo(uu[k]), v1 = bhi(uu[k]);
                if constexpr (RESCALE) { v0 *= rs; v1 *= rs; }
                s1[2 * k] += v0;     s2[2 * k] += v0 * v0;
                s1[2 * k + 1] += v1; s2[2 * k + 1] += v1 * v1;
            }
        }
    }

    __shared__ float red[2][D];
    for (int i = tid; i < 2 * D; i += 256) ((float*)red)[i] = 0.f;
    __syncthreads();
#pragma unroll
    for (int k = 0; k < VEC; ++k) {
        atomicAdd(&red[0][fb + k], s1[k]);
        atomicAdd(&red[1][fb + k], s2[k]);
    }
    __syncthreads();
    float* slot = shadow + ((blockIdx.x & (NSHADOW - 1)) << 9);
    for (int i = tid; i < 2 * D; i += 256) {
        int f = (i < D) ? i : (256 + i - D);
        float v = (i < D) ? red[0][i] : red[1][i - D];
        atomicAdd(&slot[f], v);
    }
}

// ---------------- pipelined bf16 MFMA GEMM (512 threads, 64-row tiles, register prefetch) ----------------
// AMODE: 0=f32 plain; 1=bf16, A'=sc[k]*A+sh[k] (from sums_in+gamma+beta); 2=same + sh[k]*svec[row]
// BIASRELU: out=relu(acc+bias[col]); DSCALE: out *= dinv[row]

template <int BN, int AMODE, bool BIASRELU, bool DSCALE>
__global__ __launch_bounds__(512) void k_gemm3(const void* __restrict__ Ain,
                                               const unsigned short* __restrict__ Wt,
                                               const float* __restrict__ sums_in,
                                               const float* __restrict__ gamma,
                                               const float* __restrict__ beta,
                                               const float* __restrict__ svec,
                                               const float* __restrict__ bias,
                                               const float* __restrict__ dinv,
                                               unsigned short* __restrict__ Mout,
                                               int K, int NTOT) {
    constexpr int BK = 64;
    constexpr int LDA = 72;            // +8 shorts pad, keeps 16B alignment
    constexpr int MF = 2;              // 8 waves = 2 (rows) x 4 (cols)
    constexpr int NF = BN / 64;
    constexpr int BP = BN / 64;        // B staging passes
    __shared__ unsigned short As[64 * LDA];
    __shared__ unsigned short Bs[BN * LDA];
    __shared__ float ss_sc[256];
    __shared__ float ss_sh[256];
    const int tid = threadIdx.x;
    const int lane = tid & 63;
    const int wv = tid >> 6;           // 0..7
    const int wm = wv >> 2;            // 0..1
    const int wn = wv & 3;             // 0..3
    const int row0 = blockIdx.x * 64;
    const int col0 = blockIdx.y * BN;

    if constexpr (AMODE >= 1) {
        for (int f = tid; f < K; f += 512) {
            float mean = sums_in[f] * (1.f / N_NODES);
            float var = sums_in[256 + f] * (1.f / N_NODES) - mean * mean;
            float inv = rsqrtf(var + 1e-5f);
            float sc = gamma[f] * inv;
            ss_sc[f] = sc;
            ss_sh[f] = beta[f] - mean * sc;
        }
        __syncthreads();
    }

    const int sr = tid >> 3;           // 0..63
    const int scc = (tid & 7) * 8;     // 0..56

    float4 fa[2];
    uint4 ua;
    uint4 ub[BP];
    float sv = 0.f;

    auto LOAD = [&](int k0) {
        int gr = row0 + sr;
        if constexpr (AMODE == 0) {
            const float* Af = (const float*)Ain;
            fa[0] = make_float4(0.f, 0.f, 0.f, 0.f); fa[1] = fa[0];
            if (gr < N_NODES) {
                const float* p0 = Af + (size_t)gr * K + k0 + scc;
                fa[0] = *(const float4*)p0;
                fa[1] = *(const float4*)(p0 + 4);
            }
        } else {
            const unsigned short* Ab = (const unsigned short*)Ain;
            ua = make_uint4(0, 0, 0, 0);
            if (gr < N_NODES) ua = *(const uint4*)(Ab + (size_t)gr * K + k0 + scc);
            if constexpr (AMODE == 2) sv = (gr < N_NODES) ? svec[gr] : 0.f;
        }
#pragma unroll
        for (int p = 0; p < BP; ++p)
            ub[p] = *(const uint4*)(Wt + (size_t)(col0 + p * 64 + sr) * K + k0 + scc);
    };

    auto WRITE = [&](int k0) {
        alignas(16) unsigned short tmp[8];
        if constexpr (AMODE == 0) {
            tmp[0] = f2bf(fa[0].x); tmp[1] = f2bf(fa[0].y);
            tmp[2] = f2bf(fa[0].z); tmp[3] = f2bf(fa[0].w);
            tmp[4] = f2bf(fa[1].x); tmp[5] = f2bf(fa[1].y);
            tmp[6] = f2bf(fa[1].z); tmp[7] = f2bf(fa[1].w);
        } else {
            const unsigned short* pr = (const unsigned short*)&ua;
#pragma unroll
            for (int q = 0; q < 8; ++q) {
                float sc = ss_sc[k0 + scc + q];
                float sh = ss_sh[k0 + scc + q];
                float val;
                if constexpr (AMODE == 2) val = bf2f(pr[q]) * sc + sh * sv;
                else val = bf2f(pr[q]) * sc + sh;
                tmp[q] = f2bf(val);
            }
        }
        *(uint4*)&As[sr * LDA + scc] = *(const uint4*)tmp;
#pragma unroll
        for (int p = 0; p < BP; ++p) *(uint4*)&Bs[(p * 64 + sr) * LDA + scc] = ub[p];
    };

    f32x4 acc[MF][NF];
#pragma unroll
    for (int i = 0; i < MF; ++i)
#pragma unroll
        for (int j = 0; j < NF; ++j)
#pragma unroll
            for (int r = 0; r < 4; ++r) acc[i][j][r] = 0.f;

    LOAD(0);
    WRITE(0);
    __syncthreads();
    const int nk = K / BK;
    for (int kt = 1; kt <= nk; ++kt) {
        if (kt < nk) LOAD(kt * BK);    // next-tile global loads overlap MFMA below
#pragma unroll
        for (int ks = 0; ks < 2; ++ks) {
            sh8 af[MF], bfr[NF];
#pragma unroll
            for (int i = 0; i < MF; ++i)
                af[i] = *(const sh8*)&As[(wm * 32 + i * 16 + (lane & 15)) * LDA + ks * 32 + (lane >> 4) * 8];
#pragma unroll
            for (int j = 0; j < NF; ++j)
                bfr[j] = *(const sh8*)&Bs[(wn * NF * 16 + j * 16 + (lane & 15)) * LDA + ks * 32 + (lane >> 4) * 8];
#pragma unroll
            for (int i = 0; i < MF; ++i)
#pragma unroll
                for (int j = 0; j < NF; ++j)
                    acc[i][j] = __builtin_amdgcn_mfma_f32_16x16x32_bf16(af[i], bfr[j], acc[i][j], 0, 0, 0);
        }
        __syncthreads();
        if (kt < nk) {
            WRITE(kt * BK);
            __syncthreads();
        }
    }

    // epilogue
#pragma unroll
    for (int i = 0; i < MF; ++i) {
#pragma unroll
        for (int r = 0; r < 4; ++r) {
            int grow = row0 + wm * 32 + i * 16 + (lane >> 4) * 4 + r;
            if (grow >= N_NODES) continue;
            float rsc = 1.f;
            if constexpr (DSCALE) rsc = dinv[grow];
#pragma unroll
            for (int j = 0; j < NF; ++j) {
                int gcol = col0 + wn * NF * 16 + j * 16 + (lane & 15);
                float v = acc[i][j][r];
                if constexpr (BIASRELU) v = fmaxf(v + bias[gcol], 0.f);
                if constexpr (DSCALE) v *= rsc;
                Mout[(size_t)grow * NTOT + gcol] = f2bf(v);
            }
        }
    }
}

// ---------------- aggregation: wave per node, half-wave edge split, 8B loads ----------------
// lanes 0-31 process edges [0, cnt/2), lanes 32-63 process [cnt/2, cnt); each half covers the
// full feature row (VPL = D/32, 8B loads at D=128). Final shfl_xor(32) merges halves.
// acc = sum over {edges, self} of m'[row]; POST: out = relu(di*acc + bias) [*di if OUTSCALE]; PRE: out = di*acc

template <int D, bool PRE, bool OUTF32, bool OUTSCALE>
__global__ __launch_bounds__(256) void k_agg(const unsigned short* __restrict__ m,
                                             const int* __restrict__ col,
                                             const int* __restrict__ basep,
                                             const int* __restrict__ deg,
                                             const float* __restrict__ dinv,
                                             const float* __restrict__ bias,
                                             void* __restrict__ out) {
    constexpr int VPL = D / 32;            // 128->4, 64->2
    const int w = (blockIdx.x * 256 + threadIdx.x) >> 6;
    if (w >= N_NODES) return;
    const int lane = threadIdx.x & 63;
    const int half = lane >> 5;
    const int hl = lane & 31;
    const int fo = hl * VPL;
    const unsigned short* mfo = m + fo;
    float acc[VPL];
#pragma unroll
    for (int k = 0; k < VPL; ++k) acc[k] = 0.f;

    const int start = basep[w];
    const int cnt = deg[w];
    const int c0 = cnt >> 1;
    const int jb = half ? c0 : 0;
    const int je = half ? cnt : c0;

    int j = jb;
    for (; j + 8 <= je; j += 8) {
        int sx[8];
#pragma unroll
        for (int i = 0; i < 8; ++i) sx[i] = col[start + j + i];
        if constexpr (VPL == 4) {
            uint2 u[8];
#pragma unroll
            for (int i = 0; i < 8; ++i) u[i] = *(const uint2*)(mfo + (size_t)sx[i] * D);
#pragma unroll
            for (int i = 0; i < 8; ++i) {
                acc[0] += blo(u[i].x); acc[1] += bhi(u[i].x);
                acc[2] += blo(u[i].y); acc[3] += bhi(u[i].y);
            }
        } else {
            unsigned u[8];
#pragma unroll
            for (int i = 0; i < 8; ++i) u[i] = *(const unsigned*)(mfo + (size_t)sx[i] * D);
#pragma unroll
            for (int i = 0; i < 8; ++i) { acc[0] += blo(u[i]); acc[1] += bhi(u[i]); }
        }
    }
    for (; j < je; ++j) {
        int s0 = col[start + j];
        if constexpr (VPL == 4) {
            uint2 u0 = *(const uint2*)(mfo + (size_t)s0 * D);
            acc[0] += blo(u0.x); acc[1] += bhi(u0.x);
            acc[2] += blo(u0.y); acc[3] += bhi(u0.y);
        } else {
            unsigned u0 = *(const unsigned*)(mfo + (size_t)s0 * D);
            acc[0] += blo(u0); acc[1] += bhi(u0);
        }
    }
    if (half == 0) {   // self row, added once
        if constexpr (VPL == 4) {
            uint2 u0 = *(const uint2*)(mfo + (size_t)w * D);
            acc[0] += blo(u0.x); acc[1] += bhi(u0.x);
            acc[2] += blo(u0.y); acc[3] += bhi(u0.y);
        } else {
            unsigned u0 = *(const unsigned*)(mfo + (size_t)w * D);
            acc[0] += blo(u0); acc[1] += bhi(u0);
        }
    }
    // merge halves
#pragma unroll
    for (int k = 0; k < VPL; ++k) acc[k] += __shfl_xor(acc[k], 32, 64);

    if (half != 0) return;  // half 0 finalizes and stores

    float di = dinv[w];
    float o[VPL];
    if constexpr (PRE) {
#pragma unroll
        for (int k = 0; k < VPL; ++k) o[k] = acc[k] * di;
    } else {
#pragma unroll
        for (int k = 0; k < VPL; ++k) {
            o[k] = fmaxf(acc[k] * di + bias[fo + k], 0.f);
            if constexpr (OUTSCALE) o[k] *= di;
        }
    }

    if constexpr (OUTF32) {
        float* of = (float*)out + (size_t)w * D + fo;
        if constexpr (VPL == 4) {
            *(float4*)of = make_float4(o[0], o[1], o[2], o[3]);
        } else {
            *(float2*)of = make_float2(o[0], o[1]);
        }
    } else {
        unsigned short* ob = (unsigned short*)out + (size_t)w * D + fo;
        if constexpr (VPL == 4) {
            uint2 u;
            u.x = (unsigned)f2bf(o[0]) | ((unsigned)f2bf(o[1]) << 16);
            u.y = (unsigned)f2bf(o[2]) | ((unsigned)f2bf(o[3]) << 16);
            *(uint2*)ob = u;
        } else {
            unsigned int u = (unsigned)f2bf(o[0]) | ((unsigned)f2bf(o[1]) << 16);
            *(unsigned int*)ob = u;
        }
    }
}

// ---------------- layer-4 BN finalize+apply + classifier (wave per node) ----------------

__global__ __launch_bounds__(256) void k_bnlog(const float* __restrict__ out4, const float* __restrict__ sums,
                                               const float* __restrict__ gamma, const float* __restrict__ beta,
                                               const float* __restrict__ Wc, const float* __restrict__ bc,
                                               float* __restrict__ bn4, float* __restrict__ logits) {
    int gw = (blockIdx.x * 256 + threadIdx.x) >> 6;
    if (gw >= N_NODES) return;
    int f = threadIdx.x & 63;
    float mean = sums[f] * (1.f / N_NODES);
    float var = sums[256 + f] * (1.f / N_NODES) - mean * mean;
    float inv = rsqrtf(var + 1e-5f);
    float sc = gamma[f] * inv;
    float sh = beta[f] - mean * sc;
    float v = out4[(size_t)gw * 64 + f];
    float bn = v * sc + sh;
    bn4[(size_t)gw * 64 + f] = bn;
    float a0 = bn * Wc[2 * f];
    float a1 = bn * Wc[2 * f + 1];
#pragma unroll
    for (int off = 32; off; off >>= 1) {
        a0 += __shfl_down(a0, off, 64);
        a1 += __shfl_down(a1, off, 64);
    }
    if (f == 0) {
        logits[2 * gw] = a0 + bc[0];
        logits[2 * gw + 1] = a1 + bc[1];
    }
}

// ---------------- launch ----------------

extern "C" void kernel_launch(void* const* d_in, const int* in_sizes, int n_in,
                              void* d_out, int out_size, void* d_ws, size_t ws_size,
                              hipStream_t stream) {
    const float* x  = (const float*)d_in[0];
    const int* ei   = (const int*)d_in[1];
    const float* W1 = (const float*)d_in[2];  const float* b1  = (const float*)d_in[3];
    const float* W2 = (const float*)d_in[4];  const float* b2  = (const float*)d_in[5];
    const float* W3 = (const float*)d_in[6];  const float* b3  = (const float*)d_in[7];
    const float* W4 = (const float*)d_in[8];  const float* b4  = (const float*)d_in[9];
    const float* Wc = (const float*)d_in[10]; const float* bc  = (const float*)d_in[11];
    const float* g1 = (const float*)d_in[12]; const float* be1 = (const float*)d_in[13];
    const float* g2 = (const float*)d_in[14]; const float* be2 = (const float*)d_in[15];
    const float* g3 = (const float*)d_in[16]; const float* be3 = (const float*)d_in[17];
    const float* g4 = (const float*)d_in[18]; const float* be4 = (const float*)d_in[19];

    char* wsb = (char*)d_ws;
    size_t off = 0;
    auto alloc = [&](size_t bytes) -> void* {
        void* p = wsb + off;
        off = (off + bytes + 511) & ~(size_t)511;
        return p;
    };
    int* deg     = (int*)alloc((size_t)N_NODES * 4);
    int* basep   = (int*)alloc((size_t)N_NODES * 4);
    float* dinv  = (float*)alloc((size_t)N_NODES * 4);
    float* sdeg  = (float*)alloc((size_t)N_NODES * 4);
    float* svec  = (float*)alloc((size_t)N_NODES * 4);
    int* col     = (int*)alloc((size_t)N_EDGES * 4);
    unsigned* pairs = (unsigned*)alloc((size_t)N_EDGES * 4);
    int* histG   = (int*)alloc((size_t)NB * NBLK * 4);
    int* rowsum  = (int*)alloc((size_t)NB * 4);
    int* rowbase = (int*)alloc((size_t)(NB + 1) * 4);
    float* sums  = (float*)alloc(2048 * 4);                  // 4 layer slots of 512
    float* shadow = (float*)alloc((size_t)NSHADOW * 512 * 4); // 64 shadow accumulators
    unsigned short* Wt1 = (unsigned short*)alloc((size_t)256 * 128 * 2);
    unsigned short* Wt2 = (unsigned short*)alloc((size_t)128 * 256 * 2);
    unsigned short* Wt3 = (unsigned short*)alloc((size_t)256 * 128 * 2);
    unsigned short* Wt4 = (unsigned short*)alloc((size_t)128 * 64 * 2);
    unsigned short* mb = (unsigned short*)alloc((size_t)N_NODES * 128 * 2);
    unsigned short* hb = (unsigned short*)alloc((size_t)N_NODES * 256 * 2);

    float* sums1 = sums, *sums2 = sums + 512, *sums3 = sums + 1024, *sums4 = sums + 1536;

    float* outLogits = (float*)d_out;
    float* out4 = outLogits + (size_t)N_NODES * 2;
    float* bn4  = out4 + (size_t)N_NODES * 64;

    hipMemsetAsync(sums, 0, 2048 * 4, stream);
    hipMemsetAsync(shadow, 0, (size_t)NSHADOW * 512 * 4, stream);

    // ---- CSR build: partition + bucket sort ----
    k_hist<<<NBLK, 256, 0, stream>>>(ei, histG);
    k_scanrow<<<NB, 128, 0, stream>>>(histG, rowsum);
    k_scanbkt<<<1, 512, 0, stream>>>(rowsum, rowbase);
    k_part<<<NBLK, 256, 0, stream>>>(ei, histG, rowbase, pairs);
    k_bsort<<<NB, 256, 0, stream>>>(pairs, rowbase, col, basep, deg, dinv, sdeg);
    k_svec<<<(N_NODES + 3) / 4, 256, 0, stream>>>(col, basep, deg, dinv, svec);

    k_wconv_all<<<(106496 + 255) / 256, 256, 0, stream>>>(W1, W2, W3, W4, Wt1, Wt2, Wt3, Wt4);

    const int GBM = (N_NODES + 63) / 64;   // 1563 row-tiles
    const int AB = (N_NODES + 3) / 4;      // 25000 blocks, wave per node
    const int SB = 512;                    // bnstats blocks

    // Layer 1: m1' = dinv*(x @ W1); agg -> q1 = dinv*h1 (bf16); BN1 stats on h1=q1*sdeg
    k_gemm3<128, 0, false, true><<<dim3(GBM, 1), 512, 0, stream>>>(
        x, Wt1, nullptr, nullptr, nullptr, nullptr, nullptr, dinv, mb, 256, 128);
    k_agg<128, false, false, true><<<AB, 256, 0, stream>>>(
        mb, col, basep, deg, dinv, b1, hb);
    k_bnstats<128, false, true><<<SB, 256, 0, stream>>>(hb, sdeg, shadow);
    k_bnred<<<2, 256, 0, stream>>>(shadow, sums1);

    // Layer 2 (commuted): A2 = di*(sum q1 + q1self); h2 = relu((sc1*A2 + sh1*svec) @ W2 + b2); BN2 stats
    k_agg<128, true, false, false><<<AB, 256, 0, stream>>>(
        hb, col, basep, deg, dinv, nullptr, mb);
    k_gemm3<128, 2, true, false><<<dim3(GBM, 2), 512, 0, stream>>>(
        mb, Wt2, sums1, g1, be1, svec, b2, nullptr, hb, 128, 256);
    k_bnstats<256, false, false><<<SB, 256, 0, stream>>>(hb, nullptr, shadow);
    k_bnred<<<2, 256, 0, stream>>>(shadow, sums2);

    // Layer 3: m3' = dinv*(bn2(h2) @ W3); agg+b3+relu -> h3; BN3 stats
    k_gemm3<128, 1, false, true><<<dim3(GBM, 1), 512, 0, stream>>>(
        hb, Wt3, sums2, g2, be2, nullptr, nullptr, dinv, mb, 256, 128);
    k_agg<128, false, false, false><<<AB, 256, 0, stream>>>(
        mb, col, basep, deg, dinv, b3, hb);
    k_bnstats<128, false, false><<<SB, 256, 0, stream>>>(hb, nullptr, shadow);
    k_bnred<<<2, 256, 0, stream>>>(shadow, sums3);

    // Layer 4: m4' = dinv*(bn3(h3) @ W4); agg+b4+relu -> out4 (f32); BN4 stats; classifier
    k_gemm3<64, 1, false, true><<<dim3(GBM, 1), 512, 0, stream>>>(
        hb, Wt4, sums3, g3, be3, nullptr, nullptr, dinv, mb, 128, 64);
    k_agg<64, false, true, false><<<AB, 256, 0, stream>>>(
        mb, col, basep, deg, dinv, b4, out4);
    k_bnstats<64, true, false><<<SB, 256, 0, stream>>>(out4, nullptr, shadow);
    k_bnred<<<2, 256, 0, stream>>>(shadow, sums4);
    k_bnlog<<<(N_NODES * 64 + 255) / 256, 256, 0, stream>>>(out4, sums4, g4, be4, Wc, bc, bn4, outLogits);
}

// Round 12
// 633.907 us; speedup vs baseline: 1.0399x; 1.0399x over previous
//
#include <hip/hip_runtime.h>
#include <hip/hip_bf16.h>

#define N_NODES 100000
#define N_EDGES 1600000
#define NB ((N_NODES + 255) / 256)          // 391 dst-buckets of 256 nodes
#define CHUNK 16384
#define NBLK ((N_EDGES + CHUNK - 1) / CHUNK) // 98 partition blocks
#define NSHADOW 64

typedef short sh8 __attribute__((ext_vector_type(8)));
typedef float f32x4 __attribute__((ext_vector_type(4)));

__device__ __forceinline__ float bf2f(unsigned short s) {
    return __uint_as_float(((unsigned int)s) << 16);
}
__device__ __forceinline__ unsigned short f2bf(float f) {
    unsigned int u = __float_as_uint(f);
    unsigned int r = (u + 0x7FFFu + ((u >> 16) & 1u)) >> 16;
    return (unsigned short)r;
}
__device__ __forceinline__ float blo(unsigned int u) { return __uint_as_float(u << 16); }
__device__ __forceinline__ float bhi(unsigned int u) { return __uint_as_float(u & 0xffff0000u); }

// ---------------- graph preprocessing: partition + bucket sort -> CSR ----------------

__global__ __launch_bounds__(256) void k_hist(const int* __restrict__ ei, int* __restrict__ histG) {
    __shared__ int hist[NB];
    int blk = blockIdx.x, t = threadIdx.x;
    for (int b = t; b < NB; b += 256) hist[b] = 0;
    __syncthreads();
    int e0 = blk * CHUNK;
    int e1 = min(e0 + CHUNK, N_EDGES);
    for (int e = e0 + t; e < e1; e += 256) atomicAdd(&hist[ei[N_EDGES + e] >> 8], 1);
    __syncthreads();
    for (int b = t; b < NB; b += 256) histG[b * NBLK + blk] = hist[b];
}

__global__ __launch_bounds__(128) void k_scanrow(int* __restrict__ histG, int* __restrict__ rowsum) {
    __shared__ int sm[128];
    int b = blockIdx.x, t = threadIdx.x;
    int v = (t < NBLK) ? histG[b * NBLK + t] : 0;
    sm[t] = v; __syncthreads();
    for (int d = 1; d < 128; d <<= 1) {
        int add = (t >= d) ? sm[t - d] : 0;
        __syncthreads(); sm[t] += add; __syncthreads();
    }
    if (t < NBLK) histG[b * NBLK + t] = sm[t] - v;
    if (t == 127) rowsum[b] = sm[127];
}

__global__ __launch_bounds__(512) void k_scanbkt(const int* __restrict__ rowsum, int* __restrict__ rowbase) {
    __shared__ int sm[512];
    int t = threadIdx.x;
    int v = (t < NB) ? rowsum[t] : 0;
    sm[t] = v; __syncthreads();
    for (int d = 1; d < 512; d <<= 1) {
        int add = (t >= d) ? sm[t - d] : 0;
        __syncthreads(); sm[t] += add; __syncthreads();
    }
    if (t <= NB) rowbase[t] = sm[t] - v;
}

__global__ __launch_bounds__(256) void k_part(const int* __restrict__ ei, const int* __restrict__ histG,
                                              const int* __restrict__ rowbase, unsigned* __restrict__ pairs) {
    __shared__ int cur[NB];
    int blk = blockIdx.x, t = threadIdx.x;
    for (int b = t; b < NB; b += 256) cur[b] = rowbase[b] + histG[b * NBLK + blk];
    __syncthreads();
    int e0 = blk * CHUNK;
    int e1 = min(e0 + CHUNK, N_EDGES);
    for (int e = e0 + t; e < e1; e += 256) {
        int s = ei[e], d = ei[N_EDGES + e];
        int pos = atomicAdd(&cur[d >> 8], 1);
        pairs[pos] = ((unsigned)s << 8) | (unsigned)(d & 255);
    }
}

__global__ __launch_bounds__(256) void k_bsort(const unsigned* __restrict__ pairs, const int* __restrict__ rowbase,
                                               int* __restrict__ col, int* __restrict__ basep,
                                               int* __restrict__ deg, float* __restrict__ dinv,
                                               float* __restrict__ sdeg) {
    __shared__ int cnt[256];
    __shared__ int sm[256];
    __shared__ int cur[256];
    int b = blockIdx.x, t = threadIdx.x;
    int base = rowbase[b], end = rowbase[b + 1];
    cnt[t] = 0; __syncthreads();
    for (int e = base + t; e < end; e += 256) atomicAdd(&cnt[pairs[e] & 255], 1);
    __syncthreads();
    int v = cnt[t];
    sm[t] = v; __syncthreads();
    for (int d = 1; d < 256; d <<= 1) {
        int add = (t >= d) ? sm[t - d] : 0;
        __syncthreads(); sm[t] += add; __syncthreads();
    }
    int excl = sm[t] - v;
    cur[t] = excl;
    int gd = (b << 8) + t;
    if (gd < N_NODES) {
        basep[gd] = base + excl;
        deg[gd] = v;
        dinv[gd] = rsqrtf((float)(v + 1));
        sdeg[gd] = sqrtf((float)(v + 1));
    }
    __syncthreads();
    for (int e = base + t; e < end; e += 256) {
        unsigned p = pairs[e];
        int pos = atomicAdd(&cur[p & 255], 1);
        col[base + pos] = (int)(p >> 8);
    }
}

// svec[w] = dinv[w]*(sum_e dinv[src] + dinv[w])
__global__ __launch_bounds__(256) void k_svec(const int* __restrict__ col, const int* __restrict__ basep,
                                              const int* __restrict__ deg, const float* __restrict__ dinv,
                                              float* __restrict__ svec) {
    int w = (blockIdx.x * 256 + threadIdx.x) >> 6;
    if (w >= N_NODES) return;
    int lane = threadIdx.x & 63;
    int start = basep[w], cnt = deg[w];
    float s = 0.f;
    for (int j = lane; j < cnt; j += 64) s += dinv[col[start + j]];
#pragma unroll
    for (int off = 32; off; off >>= 1) s += __shfl_down(s, off, 64);
    if (lane == 0) { float di = dinv[w]; svec[w] = di * (s + di); }
}

// ---------------- all W transpose + bf16 convert in one dispatch ----------------

__global__ void k_wconv_all(const float* __restrict__ W1, const float* __restrict__ W2,
                            const float* __restrict__ W3, const float* __restrict__ W4,
                            unsigned short* __restrict__ Wt1, unsigned short* __restrict__ Wt2,
                            unsigned short* __restrict__ Wt3, unsigned short* __restrict__ Wt4) {
    int idx = blockIdx.x * 256 + threadIdx.x;
    const float* W; unsigned short* Wt; int K, N, base;
    if (idx < 32768)       { W = W1; Wt = Wt1; K = 256; N = 128; base = 0; }
    else if (idx < 65536)  { W = W2; Wt = Wt2; K = 128; N = 256; base = 32768; }
    else if (idx < 98304)  { W = W3; Wt = Wt3; K = 256; N = 128; base = 65536; }
    else if (idx < 106496) { W = W4; Wt = Wt4; K = 128; N = 64;  base = 98304; }
    else return;
    int li = idx - base;
    int n = li / K, k = li - n * K;
    Wt[li] = f2bf(W[(size_t)k * N + n]);
}

// ---------------- shadow reduce: dst[f] = sum_s shadow[s][f]; shadow cleared ----------------

__global__ __launch_bounds__(256) void k_bnred(float* __restrict__ shadow, float* __restrict__ dst) {
    int f = blockIdx.x * 256 + threadIdx.x; // 0..511
    float s = 0.f;
#pragma unroll
    for (int i = 0; i < NSHADOW; ++i) {
        s += shadow[i * 512 + f];
        shadow[i * 512 + f] = 0.f;
    }
    dst[f] = s;
}

// ---------------- vectorized BN stats pass: shadow += per-feature {sum, sumsq} ----------------

template <int D, bool INF32, bool RESCALE>
__global__ __launch_bounds__(256) void k_bnstats(const void* __restrict__ h,
                                                 const float* __restrict__ sdeg,
                                                 float* __restrict__ shadow) {
    constexpr int VEC = INF32 ? 4 : 8;
    constexpr int TPR = D / VEC;           // threads per row
    constexpr int RPB = 256 / TPR;         // rows in flight per block
    const int tid = threadIdx.x;
    const int rg = tid / TPR;
    const int oc = tid % TPR;
    const int fb = oc * VEC;

    float s1[VEC], s2[VEC];
#pragma unroll
    for (int k = 0; k < VEC; ++k) { s1[k] = 0.f; s2[k] = 0.f; }

    for (int r = blockIdx.x * RPB + rg; r < N_NODES; r += gridDim.x * RPB) {
        float rs = 1.f;
        if constexpr (RESCALE) rs = sdeg[r];
        if constexpr (INF32) {
            float4 v = *(const float4*)((const float*)h + (size_t)r * D + fb);
            float vv[4] = {v.x, v.y, v.z, v.w};
#pragma unroll
            for (int k = 0; k < 4; ++k) {
                float val = vv[k];
                if constexpr (RESCALE) val *= rs;
                s1[k] += val; s2[k] += val * val;
            }
        } else {
            uint4 u = *(const uint4*)((const unsigned short*)h + (size_t)r * D + fb);
            unsigned uu[4] = {u.x, u.y, u.z, u.w};
#pragma unroll
            for (int k = 0; k < 4; ++k) {
                float v0 = blo(uu[k]), v1 = bhi(uu[k]);
                if constexpr (RESCALE) { v0 *= rs; v1 *= rs; }
                s1[2 * k] += v0;     s2[2 * k] += v0 * v0;
                s1[2 * k + 1] += v1; s2[2 * k + 1] += v1 * v1;
            }
        }
    }

    __shared__ float red[2][D];
    for (int i = tid; i < 2 * D; i += 256) ((float*)red)[i] = 0.f;
    __syncthreads();
#pragma unroll
    for (int k = 0; k < VEC; ++k) {
        atomicAdd(&red[0][fb + k], s1[k]);
        atomicAdd(&red[1][fb + k], s2[k]);
    }
    __syncthreads();
    float* slot = shadow + ((blockIdx.x & (NSHADOW - 1)) << 9);
    for (int i = tid; i < 2 * D; i += 256) {
        int f = (i < D) ? i : (256 + i - D);
        float v = (i < D) ? red[0][i] : red[1][i - D];
        atomicAdd(&slot[f], v);
    }
}

// ---------------- pipelined bf16 MFMA GEMM (512 threads, BMxBN tiles, register prefetch) ----------------
// AMODE: 0=f32 plain; 1=bf16, A'=sc[k]*A+sh[k] (from sums_in+gamma+beta); 2=same + sh[k]*svec[row]
// BIASRELU: out=relu(acc+bias[col]); DSCALE: out *= dinv[row]

template <int BM, int BN, int AMODE, bool BIASRELU, bool DSCALE>
__global__ __launch_bounds__(512) void k_gemm4(const void* __restrict__ Ain,
                                               const unsigned short* __restrict__ Wt,
                                               const float* __restrict__ sums_in,
                                               const float* __restrict__ gamma,
                                               const float* __restrict__ beta,
                                               const float* __restrict__ svec,
                                               const float* __restrict__ bias,
                                               const float* __restrict__ dinv,
                                               unsigned short* __restrict__ Mout,
                                               int K, int NTOT) {
    constexpr int BK = 64;
    constexpr int LDA = 72;            // +8 shorts pad, keeps 16B alignment
    constexpr int AP = BM / 64;        // A staging passes
    constexpr int BP = BN / 64;        // B staging passes
    constexpr int MF = BM / 32;        // fragments per wave (2 wave-rows)
    constexpr int NF = BN / 64;        // fragments per wave (4 wave-cols)
    __shared__ unsigned short As[BM * LDA];
    __shared__ unsigned short Bs[BN * LDA];
    __shared__ float ss_sc[256];
    __shared__ float ss_sh[256];
    const int tid = threadIdx.x;
    const int lane = tid & 63;
    const int wv = tid >> 6;           // 0..7
    const int wm = wv >> 2;            // 0..1
    const int wn = wv & 3;             // 0..3
    const int row0 = blockIdx.x * BM;
    const int col0 = blockIdx.y * BN;

    if constexpr (AMODE >= 1) {
        for (int f = tid; f < K; f += 512) {
            float mean = sums_in[f] * (1.f / N_NODES);
            float var = sums_in[256 + f] * (1.f / N_NODES) - mean * mean;
            float inv = rsqrtf(var + 1e-5f);
            float sc = gamma[f] * inv;
            ss_sc[f] = sc;
            ss_sh[f] = beta[f] - mean * sc;
        }
        __syncthreads();
    }

    const int sr = tid >> 3;           // 0..63
    const int scc = (tid & 7) * 8;     // 0..56

    float4 fa[AP][2];
    uint4 ua[AP];
    uint4 ub[BP];
    float sv[AP];

    auto LOAD = [&](int k0) {
#pragma unroll
        for (int p = 0; p < AP; ++p) {
            int gr = row0 + p * 64 + sr;
            if constexpr (AMODE == 0) {
                const float* Af = (const float*)Ain;
                fa[p][0] = make_float4(0.f, 0.f, 0.f, 0.f); fa[p][1] = fa[p][0];
                if (gr < N_NODES) {
                    const float* p0 = Af + (size_t)gr * K + k0 + scc;
                    fa[p][0] = *(const float4*)p0;
                    fa[p][1] = *(const float4*)(p0 + 4);
                }
            } else {
                const unsigned short* Ab = (const unsigned short*)Ain;
                ua[p] = make_uint4(0, 0, 0, 0);
                if (gr < N_NODES) ua[p] = *(const uint4*)(Ab + (size_t)gr * K + k0 + scc);
                if constexpr (AMODE == 2) sv[p] = (gr < N_NODES) ? svec[gr] : 0.f;
            }
        }
#pragma unroll
        for (int p = 0; p < BP; ++p)
            ub[p] = *(const uint4*)(Wt + (size_t)(col0 + p * 64 + sr) * K + k0 + scc);
    };

    auto WRITE = [&](int k0) {
#pragma unroll
        for (int p = 0; p < AP; ++p) {
            alignas(16) unsigned short tmp[8];
            if constexpr (AMODE == 0) {
                tmp[0] = f2bf(fa[p][0].x); tmp[1] = f2bf(fa[p][0].y);
                tmp[2] = f2bf(fa[p][0].z); tmp[3] = f2bf(fa[p][0].w);
                tmp[4] = f2bf(fa[p][1].x); tmp[5] = f2bf(fa[p][1].y);
                tmp[6] = f2bf(fa[p][1].z); tmp[7] = f2bf(fa[p][1].w);
            } else {
                const unsigned short* pr = (const unsigned short*)&ua[p];
#pragma unroll
                for (int q = 0; q < 8; ++q) {
                    float sc = ss_sc[k0 + scc + q];
                    float sh = ss_sh[k0 + scc + q];
                    float val;
                    if constexpr (AMODE == 2) val = bf2f(pr[q]) * sc + sh * sv[p];
                    else val = bf2f(pr[q]) * sc + sh;
                    tmp[q] = f2bf(val);
                }
            }
            *(uint4*)&As[(p * 64 + sr) * LDA + scc] = *(const uint4*)tmp;
        }
#pragma unroll
        for (int p = 0; p < BP; ++p) *(uint4*)&Bs[(p * 64 + sr) * LDA + scc] = ub[p];
    };

    f32x4 acc[MF][NF];
#pragma unroll
    for (int i = 0; i < MF; ++i)
#pragma unroll
        for (int j = 0; j < NF; ++j)
#pragma unroll
            for (int r = 0; r < 4; ++r) acc[i][j][r] = 0.f;

    LOAD(0);
    WRITE(0);
    __syncthreads();
    const int nk = K / BK;
    for (int kt = 1; kt <= nk; ++kt) {
        if (kt < nk) LOAD(kt * BK);    // next-tile global loads overlap MFMA below
#pragma unroll
        for (int ks = 0; ks < 2; ++ks) {
            sh8 af[MF], bfr[NF];
#pragma unroll
            for (int i = 0; i < MF; ++i)
                af[i] = *(const sh8*)&As[(wm * (BM / 2) + i * 16 + (lane & 15)) * LDA + ks * 32 + (lane >> 4) * 8];
#pragma unroll
            for (int j = 0; j < NF; ++j)
                bfr[j] = *(const sh8*)&Bs[(wn * NF * 16 + j * 16 + (lane & 15)) * LDA + ks * 32 + (lane >> 4) * 8];
#pragma unroll
            for (int i = 0; i < MF; ++i)
#pragma unroll
                for (int j = 0; j < NF; ++j)
                    acc[i][j] = __builtin_amdgcn_mfma_f32_16x16x32_bf16(af[i], bfr[j], acc[i][j], 0, 0, 0);
        }
        __syncthreads();
        if (kt < nk) {
            WRITE(kt * BK);
            __syncthreads();
        }
    }

    // epilogue
#pragma unroll
    for (int i = 0; i < MF; ++i) {
#pragma unroll
        for (int r = 0; r < 4; ++r) {
            int grow = row0 + wm * (BM / 2) + i * 16 + (lane >> 4) * 4 + r;
            if (grow >= N_NODES) continue;
            float rsc = 1.f;
            if constexpr (DSCALE) rsc = dinv[grow];
#pragma unroll
            for (int j = 0; j < NF; ++j) {
                int gcol = col0 + wn * NF * 16 + j * 16 + (lane & 15);
                float v = acc[i][j][r];
                if constexpr (BIASRELU) v = fmaxf(v + bias[gcol], 0.f);
                if constexpr (DSCALE) v *= rsc;
                Mout[(size_t)grow * NTOT + gcol] = f2bf(v);
            }
        }
    }
}

// ---------------- aggregation (wave per node, 4 nodes/block, unroll-8, pre-scaled messages) ----------------
// acc = sum_edges m'[src] + m'[self]
// POST: out = relu(di*acc + bias) [*di if OUTSCALE]; PRE: out = di*acc

template <int D, bool PRE, bool OUTF32, bool OUTSCALE>
__global__ __launch_bounds__(256) void k_agg(const unsigned short* __restrict__ m,
                                             const int* __restrict__ col,
                                             const int* __restrict__ basep,
                                             const int* __restrict__ deg,
                                             const float* __restrict__ dinv,
                                             const float* __restrict__ bias,
                                             void* __restrict__ out) {
    constexpr int VPL = D / 64;
    const int w = (blockIdx.x * 256 + threadIdx.x) >> 6;
    if (w >= N_NODES) return;
    const int lane = threadIdx.x & 63;
    const int fo = lane * VPL;
    const unsigned short* mfo = m + fo;
    float acc[VPL];
#pragma unroll
    for (int k = 0; k < VPL; ++k) acc[k] = 0.f;

    int start = basep[w], cnt = deg[w];
    int j = 0;
    for (; j + 8 <= cnt; j += 8) {
        int sx[8];
#pragma unroll
        for (int i = 0; i < 8; ++i) sx[i] = col[start + j + i];
        if constexpr (VPL == 2) {
            unsigned u[8];
#pragma unroll
            for (int i = 0; i < 8; ++i) u[i] = *(const unsigned*)(mfo + (size_t)sx[i] * D);
#pragma unroll
            for (int i = 0; i < 8; ++i) { acc[0] += blo(u[i]); acc[1] += bhi(u[i]); }
        } else {
            float v[8];
#pragma unroll
            for (int i = 0; i < 8; ++i) v[i] = bf2f(mfo[(size_t)sx[i] * D]);
#pragma unroll
            for (int i = 0; i < 8; ++i) acc[0] += v[i];
        }
    }
    for (; j < cnt; ++j) {
        int s0 = col[start + j];
        if constexpr (VPL == 2) {
            unsigned u0 = *(const unsigned*)(mfo + (size_t)s0 * D);
            acc[0] += blo(u0); acc[1] += bhi(u0);
        } else {
            acc[0] += bf2f(mfo[(size_t)s0 * D]);
        }
    }
    if constexpr (VPL == 2) {
        unsigned u0 = *(const unsigned*)(mfo + (size_t)w * D);
        acc[0] += blo(u0); acc[1] += bhi(u0);
    } else {
        acc[0] += bf2f(mfo[(size_t)w * D]);
    }

    float di = dinv[w];
    float o[VPL];
    if constexpr (PRE) {
#pragma unroll
        for (int k = 0; k < VPL; ++k) o[k] = acc[k] * di;
    } else {
#pragma unroll
        for (int k = 0; k < VPL; ++k) {
            o[k] = fmaxf(acc[k] * di + bias[fo + k], 0.f);
            if constexpr (OUTSCALE) o[k] *= di;
        }
    }

    if constexpr (OUTF32) {
        float* of = (float*)out;
#pragma unroll
        for (int k = 0; k < VPL; ++k) of[(size_t)w * D + fo + k] = o[k];
    } else {
        unsigned short* ob = (unsigned short*)out + (size_t)w * D + fo;
        if constexpr (VPL == 2) {
            unsigned int u = (unsigned)f2bf(o[0]) | ((unsigned)f2bf(o[1]) << 16);
            *(unsigned int*)ob = u;
        } else {
            ob[0] = f2bf(o[0]);
        }
    }
}

// ---------------- layer-4 BN finalize+apply + classifier (wave per node) ----------------

__global__ __launch_bounds__(256) void k_bnlog(const float* __restrict__ out4, const float* __restrict__ sums,
                                               const float* __restrict__ gamma, const float* __restrict__ beta,
                                               const float* __restrict__ Wc, const float* __restrict__ bc,
                                               float* __restrict__ bn4, float* __restrict__ logits) {
    int gw = (blockIdx.x * 256 + threadIdx.x) >> 6;
    if (gw >= N_NODES) return;
    int f = threadIdx.x & 63;
    float mean = sums[f] * (1.f / N_NODES);
    float var = sums[256 + f] * (1.f / N_NODES) - mean * mean;
    float inv = rsqrtf(var + 1e-5f);
    float sc = gamma[f] * inv;
    float sh = beta[f] - mean * sc;
    float v = out4[(size_t)gw * 64 + f];
    float bn = v * sc + sh;
    bn4[(size_t)gw * 64 + f] = bn;
    float a0 = bn * Wc[2 * f];
    float a1 = bn * Wc[2 * f + 1];
#pragma unroll
    for (int off = 32; off; off >>= 1) {
        a0 += __shfl_down(a0, off, 64);
        a1 += __shfl_down(a1, off, 64);
    }
    if (f == 0) {
        logits[2 * gw] = a0 + bc[0];
        logits[2 * gw + 1] = a1 + bc[1];
    }
}

// ---------------- launch ----------------

extern "C" void kernel_launch(void* const* d_in, const int* in_sizes, int n_in,
                              void* d_out, int out_size, void* d_ws, size_t ws_size,
                              hipStream_t stream) {
    const float* x  = (const float*)d_in[0];
    const int* ei   = (const int*)d_in[1];
    const float* W1 = (const float*)d_in[2];  const float* b1  = (const float*)d_in[3];
    const float* W2 = (const float*)d_in[4];  const float* b2  = (const float*)d_in[5];
    const float* W3 = (const float*)d_in[6];  const float* b3  = (const float*)d_in[7];
    const float* W4 = (const float*)d_in[8];  const float* b4  = (const float*)d_in[9];
    const float* Wc = (const float*)d_in[10]; const float* bc  = (const float*)d_in[11];
    const float* g1 = (const float*)d_in[12]; const float* be1 = (const float*)d_in[13];
    const float* g2 = (const float*)d_in[14]; const float* be2 = (const float*)d_in[15];
    const float* g3 = (const float*)d_in[16]; const float* be3 = (const float*)d_in[17];
    const float* g4 = (const float*)d_in[18]; const float* be4 = (const float*)d_in[19];

    char* wsb = (char*)d_ws;
    size_t off = 0;
    auto alloc = [&](size_t bytes) -> void* {
        void* p = wsb + off;
        off = (off + bytes + 511) & ~(size_t)511;
        return p;
    };
    int* deg     = (int*)alloc((size_t)N_NODES * 4);
    int* basep   = (int*)alloc((size_t)N_NODES * 4);
    float* dinv  = (float*)alloc((size_t)N_NODES * 4);
    float* sdeg  = (float*)alloc((size_t)N_NODES * 4);
    float* svec  = (float*)alloc((size_t)N_NODES * 4);
    int* col     = (int*)alloc((size_t)N_EDGES * 4);
    unsigned* pairs = (unsigned*)alloc((size_t)N_EDGES * 4);
    int* histG   = (int*)alloc((size_t)NB * NBLK * 4);
    int* rowsum  = (int*)alloc((size_t)NB * 4);
    int* rowbase = (int*)alloc((size_t)(NB + 1) * 4);
    float* sums  = (float*)alloc(2048 * 4);                  // 4 layer slots of 512
    float* shadow = (float*)alloc((size_t)NSHADOW * 512 * 4); // 64 shadow accumulators
    unsigned short* Wt1 = (unsigned short*)alloc((size_t)256 * 128 * 2);
    unsigned short* Wt2 = (unsigned short*)alloc((size_t)128 * 256 * 2);
    unsigned short* Wt3 = (unsigned short*)alloc((size_t)256 * 128 * 2);
    unsigned short* Wt4 = (unsigned short*)alloc((size_t)128 * 64 * 2);
    unsigned short* mb = (unsigned short*)alloc((size_t)N_NODES * 128 * 2);
    unsigned short* hb = (unsigned short*)alloc((size_t)N_NODES * 256 * 2);

    float* sums1 = sums, *sums2 = sums + 512, *sums3 = sums + 1024, *sums4 = sums + 1536;

    float* outLogits = (float*)d_out;
    float* out4 = outLogits + (size_t)N_NODES * 2;
    float* bn4  = out4 + (size_t)N_NODES * 64;

    hipMemsetAsync(sums, 0, 2048 * 4, stream);
    hipMemsetAsync(shadow, 0, (size_t)NSHADOW * 512 * 4, stream);

    // ---- CSR build: partition + bucket sort ----
    k_hist<<<NBLK, 256, 0, stream>>>(ei, histG);
    k_scanrow<<<NB, 128, 0, stream>>>(histG, rowsum);
    k_scanbkt<<<1, 512, 0, stream>>>(rowsum, rowbase);
    k_part<<<NBLK, 256, 0, stream>>>(ei, histG, rowbase, pairs);
    k_bsort<<<NB, 256, 0, stream>>>(pairs, rowbase, col, basep, deg, dinv, sdeg);
    k_svec<<<(N_NODES + 3) / 4, 256, 0, stream>>>(col, basep, deg, dinv, svec);

    k_wconv_all<<<(106496 + 255) / 256, 256, 0, stream>>>(W1, W2, W3, W4, Wt1, Wt2, Wt3, Wt4);

    const int GB128 = (N_NODES + 127) / 128; // 782 row-tiles (BM=128)
    const int GB64  = (N_NODES + 63) / 64;   // 1563 row-tiles (BM=64)
    const int AB = (N_NODES + 3) / 4;        // 25000 blocks, wave per node
    const int SB = 512;                      // bnstats blocks

    // Layer 1: m1' = dinv*(x @ W1); agg -> q1 = dinv*h1 (bf16); BN1 stats on h1=q1*sdeg
    k_gemm4<128, 128, 0, false, true><<<dim3(GB128, 1), 512, 0, stream>>>(
        x, Wt1, nullptr, nullptr, nullptr, nullptr, nullptr, dinv, mb, 256, 128);
    k_agg<128, false, false, true><<<AB, 256, 0, stream>>>(
        mb, col, basep, deg, dinv, b1, hb);
    k_bnstats<128, false, true><<<SB, 256, 0, stream>>>(hb, sdeg, shadow);
    k_bnred<<<2, 256, 0, stream>>>(shadow, sums1);

    // Layer 2 (commuted): A2 = di*(sum q1 + q1self); h2 = relu((sc1*A2 + sh1*svec) @ W2 + b2); BN2 stats
    k_agg<128, true, false, false><<<AB, 256, 0, stream>>>(
        hb, col, basep, deg, dinv, nullptr, mb);
    k_gemm4<128, 128, 2, true, false><<<dim3(GB128, 2), 512, 0, stream>>>(
        mb, Wt2, sums1, g1, be1, svec, b2, nullptr, hb, 128, 256);
    k_bnstats<256, false, false><<<SB, 256, 0, stream>>>(hb, nullptr, shadow);
    k_bnred<<<2, 256, 0, stream>>>(shadow, sums2);

    // Layer 3: m3' = dinv*(bn2(h2) @ W3); agg+b3+relu -> h3; BN3 stats
    k_gemm4<128, 128, 1, false, true><<<dim3(GB128, 1), 512, 0, stream>>>(
        hb, Wt3, sums2, g2, be2, nullptr, nullptr, dinv, mb, 256, 128);
    k_agg<128, false, false, false><<<AB, 256, 0, stream>>>(
        mb, col, basep, deg, dinv, b3, hb);
    k_bnstats<128, false, false><<<SB, 256, 0, stream>>>(hb, nullptr, shadow);
    k_bnred<<<2, 256, 0, stream>>>(shadow, sums3);

    // Layer 4: m4' = dinv*(bn3(h3) @ W4); agg+b4+relu -> out4 (f32); BN4 stats; classifier
    k_gemm4<64, 64, 1, false, true><<<dim3(GB64, 1), 512, 0, stream>>>(
        hb, Wt4, sums3, g3, be3, nullptr, nullptr, dinv, mb, 128, 64);
    k_agg<64, false, true, false><<<AB, 256, 0, stream>>>(
        mb, col, basep, deg, dinv, b4, out4);
    k_bnstats<64, true, false><<<SB, 256, 0, stream>>>(out4, nullptr, shadow);
    k_bnred<<<2, 256, 0, stream>>>(shadow, sums4);
    k_bnlog<<<(N_NODES * 64 + 255) / 256, 256, 0, stream>>>(out4, sums4, g4, be4, Wc, bc, bn4, outLogits);
}

// Round 13
// 622.117 us; speedup vs baseline: 1.0596x; 1.0190x over previous
//
#include <hip/hip_runtime.h>
#include <hip/hip_bf16.h>

#define N_NODES 100000
#define N_EDGES 1600000
#define NB ((N_NODES + 255) / 256)          // 391 dst-buckets of 256 nodes
#define CHUNK 16384
#define NBLK ((N_EDGES + CHUNK - 1) / CHUNK) // 98 partition blocks
#define NSHADOW 32
#define WCB 416                              // wconv blocks (106496 / 256)

typedef short sh8 __attribute__((ext_vector_type(8)));
typedef float f32x4 __attribute__((ext_vector_type(4)));

__device__ __forceinline__ float bf2f(unsigned short s) {
    return __uint_as_float(((unsigned int)s) << 16);
}
__device__ __forceinline__ unsigned short f2bf(float f) {
    unsigned int u = __float_as_uint(f);
    unsigned int r = (u + 0x7FFFu + ((u >> 16) & 1u)) >> 16;
    return (unsigned short)r;
}
__device__ __forceinline__ float blo(unsigned int u) { return __uint_as_float(u << 16); }
__device__ __forceinline__ float bhi(unsigned int u) { return __uint_as_float(u & 0xffff0000u); }

// ---------------- graph preprocessing: partition + bucket sort -> CSR ----------------

__global__ __launch_bounds__(256) void k_hist(const int* __restrict__ ei, int* __restrict__ histG) {
    __shared__ int hist[NB];
    int blk = blockIdx.x, t = threadIdx.x;
    for (int b = t; b < NB; b += 256) hist[b] = 0;
    __syncthreads();
    int e0 = blk * CHUNK;
    int e1 = min(e0 + CHUNK, N_EDGES);
    for (int e = e0 + t; e < e1; e += 256) atomicAdd(&hist[ei[N_EDGES + e] >> 8], 1);
    __syncthreads();
    for (int b = t; b < NB; b += 256) histG[b * NBLK + blk] = hist[b];
}

__global__ __launch_bounds__(128) void k_scanrow(int* __restrict__ histG, int* __restrict__ rowsum) {
    __shared__ int sm[128];
    int b = blockIdx.x, t = threadIdx.x;
    int v = (t < NBLK) ? histG[b * NBLK + t] : 0;
    sm[t] = v; __syncthreads();
    for (int d = 1; d < 128; d <<= 1) {
        int add = (t >= d) ? sm[t - d] : 0;
        __syncthreads(); sm[t] += add; __syncthreads();
    }
    if (t < NBLK) histG[b * NBLK + t] = sm[t] - v;
    if (t == 127) rowsum[b] = sm[127];
}

__global__ __launch_bounds__(512) void k_scanbkt(const int* __restrict__ rowsum, int* __restrict__ rowbase) {
    __shared__ int sm[512];
    int t = threadIdx.x;
    int v = (t < NB) ? rowsum[t] : 0;
    sm[t] = v; __syncthreads();
    for (int d = 1; d < 512; d <<= 1) {
        int add = (t >= d) ? sm[t - d] : 0;
        __syncthreads(); sm[t] += add; __syncthreads();
    }
    if (t <= NB) rowbase[t] = sm[t] - v;
}

__global__ __launch_bounds__(256) void k_part(const int* __restrict__ ei, const int* __restrict__ histG,
                                              const int* __restrict__ rowbase, unsigned* __restrict__ pairs) {
    __shared__ int cur[NB];
    int blk = blockIdx.x, t = threadIdx.x;
    for (int b = t; b < NB; b += 256) cur[b] = rowbase[b] + histG[b * NBLK + blk];
    __syncthreads();
    int e0 = blk * CHUNK;
    int e1 = min(e0 + CHUNK, N_EDGES);
    for (int e = e0 + t; e < e1; e += 256) {
        int s = ei[e], d = ei[N_EDGES + e];
        int pos = atomicAdd(&cur[d >> 8], 1);
        pairs[pos] = ((unsigned)s << 8) | (unsigned)(d & 255);
    }
}

__global__ __launch_bounds__(256) void k_bsort(const unsigned* __restrict__ pairs, const int* __restrict__ rowbase,
                                               int* __restrict__ col, int* __restrict__ basep,
                                               int* __restrict__ deg, float* __restrict__ dinv,
                                               float* __restrict__ sdeg) {
    __shared__ int cnt[256];
    __shared__ int sm[256];
    __shared__ int cur[256];
    int b = blockIdx.x, t = threadIdx.x;
    int base = rowbase[b], end = rowbase[b + 1];
    cnt[t] = 0; __syncthreads();
    for (int e = base + t; e < end; e += 256) atomicAdd(&cnt[pairs[e] & 255], 1);
    __syncthreads();
    int v = cnt[t];
    sm[t] = v; __syncthreads();
    for (int d = 1; d < 256; d <<= 1) {
        int add = (t >= d) ? sm[t - d] : 0;
        __syncthreads(); sm[t] += add; __syncthreads();
    }
    int excl = sm[t] - v;
    cur[t] = excl;
    int gd = (b << 8) + t;
    if (gd < N_NODES) {
        basep[gd] = base + excl;
        deg[gd] = v;
        dinv[gd] = rsqrtf((float)(v + 1));
        sdeg[gd] = sqrtf((float)(v + 1));
    }
    __syncthreads();
    for (int e = base + t; e < end; e += 256) {
        unsigned p = pairs[e];
        int pos = atomicAdd(&cur[p & 255], 1);
        col[base + pos] = (int)(p >> 8);
    }
}

// ---------------- merged: W transpose/convert + svec (one dispatch) ----------------
// blocks [0, WCB): Wt[n][k] = bf16(W[k][n]);  blocks [WCB, ...): svec wave-per-node

__global__ __launch_bounds__(256) void k_wsvec(const float* __restrict__ W1, const float* __restrict__ W2,
                                               const float* __restrict__ W3, const float* __restrict__ W4,
                                               unsigned short* __restrict__ Wt1, unsigned short* __restrict__ Wt2,
                                               unsigned short* __restrict__ Wt3, unsigned short* __restrict__ Wt4,
                                               const int* __restrict__ col, const int* __restrict__ basep,
                                               const int* __restrict__ deg, const float* __restrict__ dinv,
                                               float* __restrict__ svec) {
    if (blockIdx.x < WCB) {
        int idx = blockIdx.x * 256 + threadIdx.x;
        const float* W; unsigned short* Wt; int K, N, base;
        if (idx < 32768)       { W = W1; Wt = Wt1; K = 256; N = 128; base = 0; }
        else if (idx < 65536)  { W = W2; Wt = Wt2; K = 128; N = 256; base = 32768; }
        else if (idx < 98304)  { W = W3; Wt = Wt3; K = 256; N = 128; base = 65536; }
        else if (idx < 106496) { W = W4; Wt = Wt4; K = 128; N = 64;  base = 98304; }
        else return;
        int li = idx - base;
        int n = li / K, k = li - n * K;
        Wt[li] = f2bf(W[(size_t)k * N + n]);
        return;
    }
    int sb = blockIdx.x - WCB;
    int w = (sb * 256 + threadIdx.x) >> 6;
    if (w >= N_NODES) return;
    int lane = threadIdx.x & 63;
    int start = basep[w], cnt = deg[w];
    float s = 0.f;
    for (int j = lane; j < cnt; j += 64) s += dinv[col[start + j]];
#pragma unroll
    for (int off = 32; off; off >>= 1) s += __shfl_down(s, off, 64);
    if (lane == 0) { float di = dinv[w]; svec[w] = di * (s + di); }
}

// ---------------- shadow reduce (layer 4 only): dst[f] = sum_s arena[s][f] ----------------

__global__ __launch_bounds__(256) void k_bnred(const float* __restrict__ arena, float* __restrict__ dst) {
    int f = blockIdx.x * 256 + threadIdx.x; // 0..511
    float s = 0.f;
#pragma unroll
    for (int i = 0; i < NSHADOW; ++i) s += arena[i * 512 + f];
    dst[f] = s;
}

// ---------------- vectorized BN stats pass: arena += per-feature {sum, sumsq} ----------------

template <int D, bool INF32, bool RESCALE>
__global__ __launch_bounds__(256) void k_bnstats(const void* __restrict__ h,
                                                 const float* __restrict__ sdeg,
                                                 float* __restrict__ arena) {
    constexpr int VEC = INF32 ? 4 : 8;
    constexpr int TPR = D / VEC;           // threads per row
    constexpr int RPB = 256 / TPR;         // rows in flight per block
    const int tid = threadIdx.x;
    const int rg = tid / TPR;
    const int oc = tid % TPR;
    const int fb = oc * VEC;

    float s1[VEC], s2[VEC];
#pragma unroll
    for (int k = 0; k < VEC; ++k) { s1[k] = 0.f; s2[k] = 0.f; }

    for (int r = blockIdx.x * RPB + rg; r < N_NODES; r += gridDim.x * RPB) {
        float rs = 1.f;
        if constexpr (RESCALE) rs = sdeg[r];
        if constexpr (INF32) {
            float4 v = *(const float4*)((const float*)h + (size_t)r * D + fb);
            float vv[4] = {v.x, v.y, v.z, v.w};
#pragma unroll
            for (int k = 0; k < 4; ++k) {
                float val = vv[k];
                if constexpr (RESCALE) val *= rs;
                s1[k] += val; s2[k] += val * val;
            }
        } else {
            uint4 u = *(const uint4*)((const unsigned short*)h + (size_t)r * D + fb);
            unsigned uu[4] = {u.x, u.y, u.z, u.w};
#pragma unroll
            for (int k = 0; k < 4; ++k) {
                float v0 = blo(uu[k]), v1 = bhi(uu[k]);
                if constexpr (RESCALE) { v0 *= rs; v1 *= rs; }
                s1[2 * k] += v0;     s2[2 * k] += v0 * v0;
                s1[2 * k + 1] += v1; s2[2 * k + 1] += v1 * v1;
            }
        }
    }

    __shared__ float red[2][D];
    for (int i = tid; i < 2 * D; i += 256) ((float*)red)[i] = 0.f;
    __syncthreads();
#pragma unroll
    for (int k = 0; k < VEC; ++k) {
        atomicAdd(&red[0][fb + k], s1[k]);
        atomicAdd(&red[1][fb + k], s2[k]);
    }
    __syncthreads();
    float* slot = arena + ((blockIdx.x & (NSHADOW - 1)) << 9);
    for (int i = tid; i < 2 * D; i += 256) {
        int f = (i < D) ? i : (256 + i - D);
        float v = (i < D) ? red[0][i] : red[1][i - D];
        atomicAdd(&slot[f], v);
    }
}

// ---------------- pipelined bf16 MFMA GEMM (512 threads, BMxBN tiles, register prefetch) ----------------
// AMODE: 0=f32 plain; 1=bf16, A'=sc[k]*A+sh[k] (sc/sh computed from 32-slot shadow arena + gamma/beta);
//        2=same + sh[k]*svec[row]
// BIASRELU: out=relu(acc+bias[col]); DSCALE: out *= dinv[row]

template <int BM, int BN, int AMODE, bool BIASRELU, bool DSCALE>
__global__ __launch_bounds__(512) void k_gemm4(const void* __restrict__ Ain,
                                               const unsigned short* __restrict__ Wt,
                                               const float* __restrict__ arena,
                                               const float* __restrict__ gamma,
                                               const float* __restrict__ beta,
                                               const float* __restrict__ svec,
                                               const float* __restrict__ bias,
                                               const float* __restrict__ dinv,
                                               unsigned short* __restrict__ Mout,
                                               int K, int NTOT) {
    constexpr int BK = 64;
    constexpr int LDA = 72;            // +8 shorts pad, keeps 16B alignment
    constexpr int AP = BM / 64;        // A staging passes
    constexpr int BP = BN / 64;        // B staging passes
    constexpr int MF = BM / 32;        // fragments per wave (2 wave-rows)
    constexpr int NF = BN / 64;        // fragments per wave (4 wave-cols)
    __shared__ unsigned short As[BM * LDA];
    __shared__ unsigned short Bs[BN * LDA];
    __shared__ float ss_sc[256];
    __shared__ float ss_sh[256];
    const int tid = threadIdx.x;
    const int lane = tid & 63;
    const int wv = tid >> 6;           // 0..7
    const int wm = wv >> 2;            // 0..1
    const int wn = wv & 3;             // 0..3
    const int row0 = blockIdx.x * BM;
    const int col0 = blockIdx.y * BN;

    if constexpr (AMODE >= 1) {
        // inline shadow-arena reduce + BN finalize
        for (int f = tid; f < K; f += 512) {
            float s1 = 0.f, s2 = 0.f;
#pragma unroll
            for (int s = 0; s < NSHADOW; ++s) {
                s1 += arena[s * 512 + f];
                s2 += arena[s * 512 + 256 + f];
            }
            float mean = s1 * (1.f / N_NODES);
            float var = s2 * (1.f / N_NODES) - mean * mean;
            float inv = rsqrtf(var + 1e-5f);
            float sc = gamma[f] * inv;
            ss_sc[f] = sc;
            ss_sh[f] = beta[f] - mean * sc;
        }
        __syncthreads();
    }

    const int sr = tid >> 3;           // 0..63
    const int scc = (tid & 7) * 8;     // 0..56

    float4 fa[AP][2];
    uint4 ua[AP];
    uint4 ub[BP];
    float sv[AP];

    auto LOAD = [&](int k0) {
#pragma unroll
        for (int p = 0; p < AP; ++p) {
            int gr = row0 + p * 64 + sr;
            if constexpr (AMODE == 0) {
                const float* Af = (const float*)Ain;
                fa[p][0] = make_float4(0.f, 0.f, 0.f, 0.f); fa[p][1] = fa[p][0];
                if (gr < N_NODES) {
                    const float* p0 = Af + (size_t)gr * K + k0 + scc;
                    fa[p][0] = *(const float4*)p0;
                    fa[p][1] = *(const float4*)(p0 + 4);
                }
            } else {
                const unsigned short* Ab = (const unsigned short*)Ain;
                ua[p] = make_uint4(0, 0, 0, 0);
                if (gr < N_NODES) ua[p] = *(const uint4*)(Ab + (size_t)gr * K + k0 + scc);
                if constexpr (AMODE == 2) sv[p] = (gr < N_NODES) ? svec[gr] : 0.f;
            }
        }
#pragma unroll
        for (int p = 0; p < BP; ++p)
            ub[p] = *(const uint4*)(Wt + (size_t)(col0 + p * 64 + sr) * K + k0 + scc);
    };

    auto WRITE = [&](int k0) {
#pragma unroll
        for (int p = 0; p < AP; ++p) {
            alignas(16) unsigned short tmp[8];
            if constexpr (AMODE == 0) {
                tmp[0] = f2bf(fa[p][0].x); tmp[1] = f2bf(fa[p][0].y);
                tmp[2] = f2bf(fa[p][0].z); tmp[3] = f2bf(fa[p][0].w);
                tmp[4] = f2bf(fa[p][1].x); tmp[5] = f2bf(fa[p][1].y);
                tmp[6] = f2bf(fa[p][1].z); tmp[7] = f2bf(fa[p][1].w);
            } else {
                const unsigned short* pr = (const unsigned short*)&ua[p];
#pragma unroll
                for (int q = 0; q < 8; ++q) {
                    float sc = ss_sc[k0 + scc + q];
                    float sh = ss_sh[k0 + scc + q];
                    float val;
                    if constexpr (AMODE == 2) val = bf2f(pr[q]) * sc + sh * sv[p];
                    else val = bf2f(pr[q]) * sc + sh;
                    tmp[q] = f2bf(val);
                }
            }
            *(uint4*)&As[(p * 64 + sr) * LDA + scc] = *(const uint4*)tmp;
        }
#pragma unroll
        for (int p = 0; p < BP; ++p) *(uint4*)&Bs[(p * 64 + sr) * LDA + scc] = ub[p];
    };

    f32x4 acc[MF][NF];
#pragma unroll
    for (int i = 0; i < MF; ++i)
#pragma unroll
        for (int j = 0; j < NF; ++j)
#pragma unroll
            for (int r = 0; r < 4; ++r) acc[i][j][r] = 0.f;

    LOAD(0);
    WRITE(0);
    __syncthreads();
    const int nk = K / BK;
    for (int kt = 1; kt <= nk; ++kt) {
        if (kt < nk) LOAD(kt * BK);    // next-tile global loads overlap MFMA below
#pragma unroll
        for (int ks = 0; ks < 2; ++ks) {
            sh8 af[MF], bfr[NF];
#pragma unroll
            for (int i = 0; i < MF; ++i)
                af[i] = *(const sh8*)&As[(wm * (BM / 2) + i * 16 + (lane & 15)) * LDA + ks * 32 + (lane >> 4) * 8];
#pragma unroll
            for (int j = 0; j < NF; ++j)
                bfr[j] = *(const sh8*)&Bs[(wn * NF * 16 + j * 16 + (lane & 15)) * LDA + ks * 32 + (lane >> 4) * 8];
#pragma unroll
            for (int i = 0; i < MF; ++i)
#pragma unroll
                for (int j = 0; j < NF; ++j)
                    acc[i][j] = __builtin_amdgcn_mfma_f32_16x16x32_bf16(af[i], bfr[j], acc[i][j], 0, 0, 0);
        }
        __syncthreads();
        if (kt < nk) {
            WRITE(kt * BK);
            __syncthreads();
        }
    }

    // epilogue
#pragma unroll
    for (int i = 0; i < MF; ++i) {
#pragma unroll
        for (int r = 0; r < 4; ++r) {
            int grow = row0 + wm * (BM / 2) + i * 16 + (lane >> 4) * 4 + r;
            if (grow >= N_NODES) continue;
            float rsc = 1.f;
            if constexpr (DSCALE) rsc = dinv[grow];
#pragma unroll
            for (int j = 0; j < NF; ++j) {
                int gcol = col0 + wn * NF * 16 + j * 16 + (lane & 15);
                float v = acc[i][j][r];
                if constexpr (BIASRELU) v = fmaxf(v + bias[gcol], 0.f);
                if constexpr (DSCALE) v *= rsc;
                Mout[(size_t)grow * NTOT + gcol] = f2bf(v);
            }
        }
    }
}

// ---------------- aggregation (wave per node, 4 nodes/block, unroll-8, pre-scaled messages) ----------------
// acc = sum_edges m'[src] + m'[self]
// POST: out = relu(di*acc + bias) [*di if OUTSCALE]; PRE: out = di*acc

template <int D, bool PRE, bool OUTF32, bool OUTSCALE>
__global__ __launch_bounds__(256) void k_agg(const unsigned short* __restrict__ m,
                                             const int* __restrict__ col,
                                             const int* __restrict__ basep,
                                             const int* __restrict__ deg,
                                             const float* __restrict__ dinv,
                                             const float* __restrict__ bias,
                                             void* __restrict__ out) {
    constexpr int VPL = D / 64;
    const int w = (blockIdx.x * 256 + threadIdx.x) >> 6;
    if (w >= N_NODES) return;
    const int lane = threadIdx.x & 63;
    const int fo = lane * VPL;
    const unsigned short* mfo = m + fo;
    float acc[VPL];
#pragma unroll
    for (int k = 0; k < VPL; ++k) acc[k] = 0.f;

    int start = basep[w], cnt = deg[w];
    int j = 0;
    for (; j + 8 <= cnt; j += 8) {
        int sx[8];
#pragma unroll
        for (int i = 0; i < 8; ++i) sx[i] = col[start + j + i];
        if constexpr (VPL == 2) {
            unsigned u[8];
#pragma unroll
            for (int i = 0; i < 8; ++i) u[i] = *(const unsigned*)(mfo + (size_t)sx[i] * D);
#pragma unroll
            for (int i = 0; i < 8; ++i) { acc[0] += blo(u[i]); acc[1] += bhi(u[i]); }
        } else {
            float v[8];
#pragma unroll
            for (int i = 0; i < 8; ++i) v[i] = bf2f(mfo[(size_t)sx[i] * D]);
#pragma unroll
            for (int i = 0; i < 8; ++i) acc[0] += v[i];
        }
    }
    for (; j < cnt; ++j) {
        int s0 = col[start + j];
        if constexpr (VPL == 2) {
            unsigned u0 = *(const unsigned*)(mfo + (size_t)s0 * D);
            acc[0] += blo(u0); acc[1] += bhi(u0);
        } else {
            acc[0] += bf2f(mfo[(size_t)s0 * D]);
        }
    }
    if constexpr (VPL == 2) {
        unsigned u0 = *(const unsigned*)(mfo + (size_t)w * D);
        acc[0] += blo(u0); acc[1] += bhi(u0);
    } else {
        acc[0] += bf2f(mfo[(size_t)w * D]);
    }

    float di = dinv[w];
    float o[VPL];
    if constexpr (PRE) {
#pragma unroll
        for (int k = 0; k < VPL; ++k) o[k] = acc[k] * di;
    } else {
#pragma unroll
        for (int k = 0; k < VPL; ++k) {
            o[k] = fmaxf(acc[k] * di + bias[fo + k], 0.f);
            if constexpr (OUTSCALE) o[k] *= di;
        }
    }

    if constexpr (OUTF32) {
        float* of = (float*)out;
#pragma unroll
        for (int k = 0; k < VPL; ++k) of[(size_t)w * D + fo + k] = o[k];
    } else {
        unsigned short* ob = (unsigned short*)out + (size_t)w * D + fo;
        if constexpr (VPL == 2) {
            unsigned int u = (unsigned)f2bf(o[0]) | ((unsigned)f2bf(o[1]) << 16);
            *(unsigned int*)ob = u;
        } else {
            ob[0] = f2bf(o[0]);
        }
    }
}

// ---------------- layer-4 BN finalize+apply + classifier (wave per node) ----------------

__global__ __launch_bounds__(256) void k_bnlog(const float* __restrict__ out4, const float* __restrict__ sums,
                                               const float* __restrict__ gamma, const float* __restrict__ beta,
                                               const float* __restrict__ Wc, const float* __restrict__ bc,
                                               float* __restrict__ bn4, float* __restrict__ logits) {
    int gw = (blockIdx.x * 256 + threadIdx.x) >> 6;
    if (gw >= N_NODES) return;
    int f = threadIdx.x & 63;
    float mean = sums[f] * (1.f / N_NODES);
    float var = sums[256 + f] * (1.f / N_NODES) - mean * mean;
    float inv = rsqrtf(var + 1e-5f);
    float sc = gamma[f] * inv;
    float sh = beta[f] - mean * sc;
    float v = out4[(size_t)gw * 64 + f];
    float bn = v * sc + sh;
    bn4[(size_t)gw * 64 + f] = bn;
    float a0 = bn * Wc[2 * f];
    float a1 = bn * Wc[2 * f + 1];
#pragma unroll
    for (int off = 32; off; off >>= 1) {
        a0 += __shfl_down(a0, off, 64);
        a1 += __shfl_down(a1, off, 64);
    }
    if (f == 0) {
        logits[2 * gw] = a0 + bc[0];
        logits[2 * gw + 1] = a1 + bc[1];
    }
}

// ---------------- launch ----------------

extern "C" void kernel_launch(void* const* d_in, const int* in_sizes, int n_in,
                              void* d_out, int out_size, void* d_ws, size_t ws_size,
                              hipStream_t stream) {
    const float* x  = (const float*)d_in[0];
    const int* ei   = (const int*)d_in[1];
    const float* W1 = (const float*)d_in[2];  const float* b1  = (const float*)d_in[3];
    const float* W2 = (const float*)d_in[4];  const float* b2  = (const float*)d_in[5];
    const float* W3 = (const float*)d_in[6];  const float* b3  = (const float*)d_in[7];
    const float* W4 = (const float*)d_in[8];  const float* b4  = (const float*)d_in[9];
    const float* Wc = (const float*)d_in[10]; const float* bc  = (const float*)d_in[11];
    const float* g1 = (const float*)d_in[12]; const float* be1 = (const float*)d_in[13];
    const float* g2 = (const float*)d_in[14]; const float* be2 = (const float*)d_in[15];
    const float* g3 = (const float*)d_in[16]; const float* be3 = (const float*)d_in[17];
    const float* g4 = (const float*)d_in[18]; const float* be4 = (const float*)d_in[19];

    char* wsb = (char*)d_ws;
    size_t off = 0;
    auto alloc = [&](size_t bytes) -> void* {
        void* p = wsb + off;
        off = (off + bytes + 511) & ~(size_t)511;
        return p;
    };
    int* deg     = (int*)alloc((size_t)N_NODES * 4);
    int* basep   = (int*)alloc((size_t)N_NODES * 4);
    float* dinv  = (float*)alloc((size_t)N_NODES * 4);
    float* sdeg  = (float*)alloc((size_t)N_NODES * 4);
    float* svec  = (float*)alloc((size_t)N_NODES * 4);
    int* col     = (int*)alloc((size_t)N_EDGES * 4);
    unsigned* pairs = (unsigned*)alloc((size_t)N_EDGES * 4);
    int* histG   = (int*)alloc((size_t)NB * NBLK * 4);
    int* rowsum  = (int*)alloc((size_t)NB * 4);
    int* rowbase = (int*)alloc((size_t)(NB + 1) * 4);
    // sums (2048 f32 = 8 KB) immediately followed by 4 shadow arenas (4 x 32 x 512 f32 = 256 KB);
    // both zeroed by ONE memset below (alloc keeps them contiguous: 8 KB is 512-aligned).
    float* sums   = (float*)alloc(2048 * 4);
    float* shadow = (float*)alloc((size_t)4 * NSHADOW * 512 * 4);
    unsigned short* Wt1 = (unsigned short*)alloc((size_t)256 * 128 * 2);
    unsigned short* Wt2 = (unsigned short*)alloc((size_t)128 * 256 * 2);
    unsigned short* Wt3 = (unsigned short*)alloc((size_t)256 * 128 * 2);
    unsigned short* Wt4 = (unsigned short*)alloc((size_t)128 * 64 * 2);
    unsigned short* mb = (unsigned short*)alloc((size_t)N_NODES * 128 * 2);
    unsigned short* hb = (unsigned short*)alloc((size_t)N_NODES * 256 * 2);

    float* sums4  = sums + 1536;
    float* arena1 = shadow;
    float* arena2 = shadow + NSHADOW * 512;
    float* arena3 = shadow + 2 * NSHADOW * 512;
    float* arena4 = shadow + 3 * NSHADOW * 512;

    float* outLogits = (float*)d_out;
    float* out4 = outLogits + (size_t)N_NODES * 2;
    float* bn4  = out4 + (size_t)N_NODES * 64;

    // single memset covers sums + all shadow arenas (contiguous)
    hipMemsetAsync(sums, 0, 2048 * 4 + (size_t)4 * NSHADOW * 512 * 4, stream);

    // ---- CSR build: partition + bucket sort ----
    k_hist<<<NBLK, 256, 0, stream>>>(ei, histG);
    k_scanrow<<<NB, 128, 0, stream>>>(histG, rowsum);
    k_scanbkt<<<1, 512, 0, stream>>>(rowsum, rowbase);
    k_part<<<NBLK, 256, 0, stream>>>(ei, histG, rowbase, pairs);
    k_bsort<<<NB, 256, 0, stream>>>(pairs, rowbase, col, basep, deg, dinv, sdeg);
    k_wsvec<<<WCB + (N_NODES + 3) / 4, 256, 0, stream>>>(W1, W2, W3, W4, Wt1, Wt2, Wt3, Wt4,
                                                         col, basep, deg, dinv, svec);

    const int GB128 = (N_NODES + 127) / 128; // 782 row-tiles (BM=128)
    const int GB64  = (N_NODES + 63) / 64;   // 1563 row-tiles (BM=64)
    const int AB = (N_NODES + 3) / 4;        // 25000 blocks, wave per node
    const int SB = 512;                      // bnstats blocks

    // Layer 1: m1' = dinv*(x @ W1); agg -> q1 = dinv*h1 (bf16); BN1 stats (arena1) on h1=q1*sdeg
    k_gemm4<128, 128, 0, false, true><<<dim3(GB128, 1), 512, 0, stream>>>(
        x, Wt1, nullptr, nullptr, nullptr, nullptr, nullptr, dinv, mb, 256, 128);
    k_agg<128, false, false, true><<<AB, 256, 0, stream>>>(
        mb, col, basep, deg, dinv, b1, hb);
    k_bnstats<128, false, true><<<SB, 256, 0, stream>>>(hb, sdeg, arena1);

    // Layer 2 (commuted): A2 = di*(sum q1 + q1self); h2 = relu((sc1*A2 + sh1*svec) @ W2 + b2); BN2 stats (arena2)
    k_agg<128, true, false, false><<<AB, 256, 0, stream>>>(
        hb, col, basep, deg, dinv, nullptr, mb);
    k_gemm4<128, 128, 2, true, false><<<dim3(GB128, 2), 512, 0, stream>>>(
        mb, Wt2, arena1, g1, be1, svec, b2, nullptr, hb, 128, 256);
    k_bnstats<256, false, false><<<SB, 256, 0, stream>>>(hb, nullptr, arena2);

    // Layer 3: m3' = dinv*(bn2(h2) @ W3); agg+b3+relu -> h3; BN3 stats (arena3)
    k_gemm4<128, 128, 1, false, true><<<dim3(GB128, 1), 512, 0, stream>>>(
        hb, Wt3, arena2, g2, be2, nullptr, nullptr, dinv, mb, 256, 128);
    k_agg<128, false, false, false><<<AB, 256, 0, stream>>>(
        mb, col, basep, deg, dinv, b3, hb);
    k_bnstats<128, false, false><<<SB, 256, 0, stream>>>(hb, nullptr, arena3);

    // Layer 4: m4' = dinv*(bn3(h3) @ W4); agg+b4+relu -> out4 (f32); BN4 stats (arena4); classifier
    k_gemm4<64, 64, 1, false, true><<<dim3(GB64, 1), 512, 0, stream>>>(
        hb, Wt4, arena3, g3, be3, nullptr, nullptr, dinv, mb, 128, 64);
    k_agg<64, false, true, false><<<AB, 256, 0, stream>>>(
        mb, col, basep, deg, dinv, b4, out4);
    k_bnstats<64, true, false><<<SB, 256, 0, stream>>>(out4, nullptr, arena4);
    k_bnred<<<2, 256, 0, stream>>>(arena4, sums4);
    k_bnlog<<<(N_NODES * 64 + 255) / 256, 256, 0, stream>>>(out4, sums4, g4, be4, Wc, bc, bn4, outLogits);
}

// Round 14
// 588.150 us; speedup vs baseline: 1.1208x; 1.0578x over previous
//
#include <hip/hip_runtime.h>
#include <hip/hip_bf16.h>

#define N_NODES 100000
#define N_EDGES 1600000
#define NB ((N_NODES + 255) / 256)          // 391 dst-buckets of 256 nodes
#define CHUNK 16384
#define NBLK ((N_EDGES + CHUNK - 1) / CHUNK) // 98 partition blocks
#define NSHADOW 32
#define WCB 416                              // wconv blocks (106496 / 256)
#define SB 512                               // bnstats blocks

typedef short sh8 __attribute__((ext_vector_type(8)));
typedef float f32x4 __attribute__((ext_vector_type(4)));

__device__ __forceinline__ float bf2f(unsigned short s) {
    return __uint_as_float(((unsigned int)s) << 16);
}
__device__ __forceinline__ unsigned short f2bf(float f) {
    unsigned int u = __float_as_uint(f);
    unsigned int r = (u + 0x7FFFu + ((u >> 16) & 1u)) >> 16;
    return (unsigned short)r;
}
__device__ __forceinline__ float blo(unsigned int u) { return __uint_as_float(u << 16); }
__device__ __forceinline__ float bhi(unsigned int u) { return __uint_as_float(u & 0xffff0000u); }

// ---------------- graph preprocessing: partition + bucket sort -> CSR ----------------

__global__ __launch_bounds__(256) void k_hist(const int* __restrict__ ei, int* __restrict__ histG) {
    __shared__ int hist[NB];
    int blk = blockIdx.x, t = threadIdx.x;
    for (int b = t; b < NB; b += 256) hist[b] = 0;
    __syncthreads();
    int e0 = blk * CHUNK;
    int e1 = min(e0 + CHUNK, N_EDGES);
    for (int e = e0 + t; e < e1; e += 256) atomicAdd(&hist[ei[N_EDGES + e] >> 8], 1);
    __syncthreads();
    for (int b = t; b < NB; b += 256) histG[b * NBLK + blk] = hist[b];
}

__global__ __launch_bounds__(128) void k_scanrow(int* __restrict__ histG, int* __restrict__ rowsum) {
    __shared__ int sm[128];
    int b = blockIdx.x, t = threadIdx.x;
    int v = (t < NBLK) ? histG[b * NBLK + t] : 0;
    sm[t] = v; __syncthreads();
    for (int d = 1; d < 128; d <<= 1) {
        int add = (t >= d) ? sm[t - d] : 0;
        __syncthreads(); sm[t] += add; __syncthreads();
    }
    if (t < NBLK) histG[b * NBLK + t] = sm[t] - v;
    if (t == 127) rowsum[b] = sm[127];
}

__global__ __launch_bounds__(512) void k_scanbkt(const int* __restrict__ rowsum, int* __restrict__ rowbase) {
    __shared__ int sm[512];
    int t = threadIdx.x;
    int v = (t < NB) ? rowsum[t] : 0;
    sm[t] = v; __syncthreads();
    for (int d = 1; d < 512; d <<= 1) {
        int add = (t >= d) ? sm[t - d] : 0;
        __syncthreads(); sm[t] += add; __syncthreads();
    }
    if (t <= NB) rowbase[t] = sm[t] - v;
}

__global__ __launch_bounds__(256) void k_part(const int* __restrict__ ei, const int* __restrict__ histG,
                                              const int* __restrict__ rowbase, unsigned* __restrict__ pairs) {
    __shared__ int cur[NB];
    int blk = blockIdx.x, t = threadIdx.x;
    for (int b = t; b < NB; b += 256) cur[b] = rowbase[b] + histG[b * NBLK + blk];
    __syncthreads();
    int e0 = blk * CHUNK;
    int e1 = min(e0 + CHUNK, N_EDGES);
    for (int e = e0 + t; e < e1; e += 256) {
        int s = ei[e], d = ei[N_EDGES + e];
        int pos = atomicAdd(&cur[d >> 8], 1);
        pairs[pos] = ((unsigned)s << 8) | (unsigned)(d & 255);
    }
}

__global__ __launch_bounds__(256) void k_bsort(const unsigned* __restrict__ pairs, const int* __restrict__ rowbase,
                                               int* __restrict__ col, int* __restrict__ basep,
                                               int* __restrict__ deg, float* __restrict__ dinv,
                                               float* __restrict__ sdeg) {
    __shared__ int cnt[256];
    __shared__ int sm[256];
    __shared__ int cur[256];
    int b = blockIdx.x, t = threadIdx.x;
    int base = rowbase[b], end = rowbase[b + 1];
    cnt[t] = 0; __syncthreads();
    for (int e = base + t; e < end; e += 256) atomicAdd(&cnt[pairs[e] & 255], 1);
    __syncthreads();
    int v = cnt[t];
    sm[t] = v; __syncthreads();
    for (int d = 1; d < 256; d <<= 1) {
        int add = (t >= d) ? sm[t - d] : 0;
        __syncthreads(); sm[t] += add; __syncthreads();
    }
    int excl = sm[t] - v;
    cur[t] = excl;
    int gd = (b << 8) + t;
    if (gd < N_NODES) {
        basep[gd] = base + excl;
        deg[gd] = v;
        dinv[gd] = rsqrtf((float)(v + 1));
        sdeg[gd] = sqrtf((float)(v + 1));
    }
    __syncthreads();
    for (int e = base + t; e < end; e += 256) {
        unsigned p = pairs[e];
        int pos = atomicAdd(&cur[p & 255], 1);
        col[base + pos] = (int)(p >> 8);
    }
}

// ---------------- merged: W transpose/convert + svec (one dispatch) ----------------

__global__ __launch_bounds__(256) void k_wsvec(const float* __restrict__ W1, const float* __restrict__ W2,
                                               const float* __restrict__ W3, const float* __restrict__ W4,
                                               unsigned short* __restrict__ Wt1, unsigned short* __restrict__ Wt2,
                                               unsigned short* __restrict__ Wt3, unsigned short* __restrict__ Wt4,
                                               const int* __restrict__ col, const int* __restrict__ basep,
                                               const int* __restrict__ deg, const float* __restrict__ dinv,
                                               float* __restrict__ svec) {
    if (blockIdx.x < WCB) {
        int idx = blockIdx.x * 256 + threadIdx.x;
        const float* W; unsigned short* Wt; int K, N, base;
        if (idx < 32768)       { W = W1; Wt = Wt1; K = 256; N = 128; base = 0; }
        else if (idx < 65536)  { W = W2; Wt = Wt2; K = 128; N = 256; base = 32768; }
        else if (idx < 98304)  { W = W3; Wt = Wt3; K = 256; N = 128; base = 65536; }
        else if (idx < 106496) { W = W4; Wt = Wt4; K = 128; N = 64;  base = 98304; }
        else return;
        int li = idx - base;
        int n = li / K, k = li - n * K;
        Wt[li] = f2bf(W[(size_t)k * N + n]);
        return;
    }
    int sb = blockIdx.x - WCB;
    int w = (sb * 256 + threadIdx.x) >> 6;
    if (w >= N_NODES) return;
    int lane = threadIdx.x & 63;
    int start = basep[w], cnt = deg[w];
    float s = 0.f;
    for (int j = lane; j < cnt; j += 64) s += dinv[col[start + j]];
#pragma unroll
    for (int off = 32; off; off >>= 1) s += __shfl_down(s, off, 64);
    if (lane == 0) { float di = dinv[w]; svec[w] = di * (s + di); }
}

// ---------------- shadow reduce (layer 4 only): dst[f] = sum_s arena[s][f] ----------------

__global__ __launch_bounds__(256) void k_bnred(const float* __restrict__ arena, float* __restrict__ dst) {
    int f = blockIdx.x * 256 + threadIdx.x; // 0..511
    float s = 0.f;
#pragma unroll
    for (int i = 0; i < NSHADOW; ++i) s += arena[i * 512 + f];
    dst[f] = s;
}

// ---------------- BN stats body: arena += per-feature {sum, sumsq} ----------------

template <int D, bool INF32, bool RESCALE>
__device__ __forceinline__ void bnstats_body(int bid, int gridN, const void* __restrict__ h,
                                             const float* __restrict__ sdeg, float* __restrict__ arena) {
    constexpr int VEC = INF32 ? 4 : 8;
    constexpr int TPR = D / VEC;
    constexpr int RPB = 256 / TPR;
    const int tid = threadIdx.x;
    const int rg = tid / TPR;
    const int oc = tid % TPR;
    const int fb = oc * VEC;

    float s1[VEC], s2[VEC];
#pragma unroll
    for (int k = 0; k < VEC; ++k) { s1[k] = 0.f; s2[k] = 0.f; }

    for (int r = bid * RPB + rg; r < N_NODES; r += gridN * RPB) {
        float rs = 1.f;
        if constexpr (RESCALE) rs = sdeg[r];
        if constexpr (INF32) {
            float4 v = *(const float4*)((const float*)h + (size_t)r * D + fb);
            float vv[4] = {v.x, v.y, v.z, v.w};
#pragma unroll
            for (int k = 0; k < 4; ++k) {
                float val = vv[k];
                if constexpr (RESCALE) val *= rs;
                s1[k] += val; s2[k] += val * val;
            }
        } else {
            uint4 u = *(const uint4*)((const unsigned short*)h + (size_t)r * D + fb);
            unsigned uu[4] = {u.x, u.y, u.z, u.w};
#pragma unroll
            for (int k = 0; k < 4; ++k) {
                float v0 = blo(uu[k]), v1 = bhi(uu[k]);
                if constexpr (RESCALE) { v0 *= rs; v1 *= rs; }
                s1[2 * k] += v0;     s2[2 * k] += v0 * v0;
                s1[2 * k + 1] += v1; s2[2 * k + 1] += v1 * v1;
            }
        }
    }

    __shared__ float red[2][D];
    for (int i = tid; i < 2 * D; i += 256) ((float*)red)[i] = 0.f;
    __syncthreads();
#pragma unroll
    for (int k = 0; k < VEC; ++k) {
        atomicAdd(&red[0][fb + k], s1[k]);
        atomicAdd(&red[1][fb + k], s2[k]);
    }
    __syncthreads();
    float* slot = arena + ((bid & (NSHADOW - 1)) << 9);
    for (int i = tid; i < 2 * D; i += 256) {
        int f = (i < D) ? i : (256 + i - D);
        float v = (i < D) ? red[0][i] : red[1][i - D];
        atomicAdd(&slot[f], v);
    }
}

template <int D, bool INF32, bool RESCALE>
__global__ __launch_bounds__(256) void k_bnstats(const void* __restrict__ h,
                                                 const float* __restrict__ sdeg,
                                                 float* __restrict__ arena) {
    bnstats_body<D, INF32, RESCALE>(blockIdx.x, gridDim.x, h, sdeg, arena);
}

// ---------------- aggregation body (wave per node, unroll-8) ----------------
// acc = sum_edges m'[src] + m'[self]
// POST: out = relu(di*acc + bias) [*di if OUTSCALE]; PRE: out = di*acc

template <int D, bool PRE, bool OUTF32, bool OUTSCALE>
__device__ __forceinline__ void agg_body(int bid, const unsigned short* __restrict__ m,
                                         const int* __restrict__ col,
                                         const int* __restrict__ basep,
                                         const int* __restrict__ deg,
                                         const float* __restrict__ dinv,
                                         const float* __restrict__ bias,
                                         void* __restrict__ out) {
    constexpr int VPL = D / 64;
    const int w = (bid * 256 + threadIdx.x) >> 6;
    if (w >= N_NODES) return;
    const int lane = threadIdx.x & 63;
    const int fo = lane * VPL;
    const unsigned short* mfo = m + fo;
    float acc[VPL];
#pragma unroll
    for (int k = 0; k < VPL; ++k) acc[k] = 0.f;

    int start = basep[w], cnt = deg[w];
    int j = 0;
    for (; j + 8 <= cnt; j += 8) {
        int sx[8];
#pragma unroll
        for (int i = 0; i < 8; ++i) sx[i] = col[start + j + i];
        if constexpr (VPL == 2) {
            unsigned u[8];
#pragma unroll
            for (int i = 0; i < 8; ++i) u[i] = *(const unsigned*)(mfo + (size_t)sx[i] * D);
#pragma unroll
            for (int i = 0; i < 8; ++i) { acc[0] += blo(u[i]); acc[1] += bhi(u[i]); }
        } else {
            float v[8];
#pragma unroll
            for (int i = 0; i < 8; ++i) v[i] = bf2f(mfo[(size_t)sx[i] * D]);
#pragma unroll
            for (int i = 0; i < 8; ++i) acc[0] += v[i];
        }
    }
    for (; j < cnt; ++j) {
        int s0 = col[start + j];
        if constexpr (VPL == 2) {
            unsigned u0 = *(const unsigned*)(mfo + (size_t)s0 * D);
            acc[0] += blo(u0); acc[1] += bhi(u0);
        } else {
            acc[0] += bf2f(mfo[(size_t)s0 * D]);
        }
    }
    if constexpr (VPL == 2) {
        unsigned u0 = *(const unsigned*)(mfo + (size_t)w * D);
        acc[0] += blo(u0); acc[1] += bhi(u0);
    } else {
        acc[0] += bf2f(mfo[(size_t)w * D]);
    }

    float di = dinv[w];
    float o[VPL];
    if constexpr (PRE) {
#pragma unroll
        for (int k = 0; k < VPL; ++k) o[k] = acc[k] * di;
    } else {
#pragma unroll
        for (int k = 0; k < VPL; ++k) {
            o[k] = fmaxf(acc[k] * di + bias[fo + k], 0.f);
            if constexpr (OUTSCALE) o[k] *= di;
        }
    }

    if constexpr (OUTF32) {
        float* of = (float*)out;
#pragma unroll
        for (int k = 0; k < VPL; ++k) of[(size_t)w * D + fo + k] = o[k];
    } else {
        unsigned short* ob = (unsigned short*)out + (size_t)w * D + fo;
        if constexpr (VPL == 2) {
            unsigned int u = (unsigned)f2bf(o[0]) | ((unsigned)f2bf(o[1]) << 16);
            *(unsigned int*)ob = u;
        } else {
            ob[0] = f2bf(o[0]);
        }
    }
}

template <int D, bool PRE, bool OUTF32, bool OUTSCALE>
__global__ __launch_bounds__(256) void k_agg(const unsigned short* __restrict__ m,
                                             const int* __restrict__ col,
                                             const int* __restrict__ basep,
                                             const int* __restrict__ deg,
                                             const float* __restrict__ dinv,
                                             const float* __restrict__ bias,
                                             void* __restrict__ out) {
    agg_body<D, PRE, OUTF32, OUTSCALE>(blockIdx.x, m, col, basep, deg, dinv, bias, out);
}

// ---------------- fused: BN1 stats (blocks [0,SB)) || L2 PRE agg (blocks [SB, ...)) ----------------
// both only READ hb; independent.

__global__ __launch_bounds__(256) void k_aggpre_stats(const unsigned short* __restrict__ hb,
                                                      const int* __restrict__ col,
                                                      const int* __restrict__ basep,
                                                      const int* __restrict__ deg,
                                                      const float* __restrict__ dinv,
                                                      const float* __restrict__ sdeg,
                                                      unsigned short* __restrict__ mb,
                                                      float* __restrict__ arena) {
    if (blockIdx.x < SB) {
        bnstats_body<128, false, true>(blockIdx.x, SB, hb, sdeg, arena);
    } else {
        agg_body<128, true, false, false>(blockIdx.x - SB, hb, col, basep, deg, dinv, nullptr, mb);
    }
}

// ---------------- D=64 aggregation: half-wave per node, 4B loads ----------------

template <bool OUTF32>
__global__ __launch_bounds__(256) void k_agg64(const unsigned short* __restrict__ m,
                                               const int* __restrict__ col,
                                               const int* __restrict__ basep,
                                               const int* __restrict__ deg,
                                               const float* __restrict__ dinv,
                                               const float* __restrict__ bias,
                                               void* __restrict__ out) {
    const int w = (blockIdx.x * 256 + threadIdx.x) >> 5;  // node per half-wave
    if (w >= N_NODES) return;
    const int hl = threadIdx.x & 31;
    const int fo = hl * 2;
    const unsigned short* mfo = m + fo;
    float acc0 = 0.f, acc1 = 0.f;

    int start = basep[w], cnt = deg[w];
    int j = 0;
    for (; j + 8 <= cnt; j += 8) {
        int sx[8];
#pragma unroll
        for (int i = 0; i < 8; ++i) sx[i] = col[start + j + i];
        unsigned u[8];
#pragma unroll
        for (int i = 0; i < 8; ++i) u[i] = *(const unsigned*)(mfo + (size_t)sx[i] * 64);
#pragma unroll
        for (int i = 0; i < 8; ++i) { acc0 += blo(u[i]); acc1 += bhi(u[i]); }
    }
    for (; j < cnt; ++j) {
        int s0 = col[start + j];
        unsigned u0 = *(const unsigned*)(mfo + (size_t)s0 * 64);
        acc0 += blo(u0); acc1 += bhi(u0);
    }
    {
        unsigned u0 = *(const unsigned*)(mfo + (size_t)w * 64);
        acc0 += blo(u0); acc1 += bhi(u0);
    }

    float di = dinv[w];
    float o0 = fmaxf(acc0 * di + bias[fo], 0.f);
    float o1 = fmaxf(acc1 * di + bias[fo + 1], 0.f);

    if constexpr (OUTF32) {
        *(float2*)((float*)out + (size_t)w * 64 + fo) = make_float2(o0, o1);
    } else {
        unsigned u = (unsigned)f2bf(o0) | ((unsigned)f2bf(o1) << 16);
        *(unsigned*)((unsigned short*)out + (size_t)w * 64 + fo) = u;
    }
}

// ---------------- pipelined bf16 MFMA GEMM (512 threads, BMxBN tiles, register prefetch) ----------------
// AMODE: 0=f32 plain; 1=bf16, A'=sc[k]*A+sh[k] (sc/sh from 32-slot shadow arena + gamma/beta);
//        2=same + sh[k]*svec[row]
// BIASRELU: out=relu(acc+bias[col]); DSCALE: out *= dinv[row]

template <int BM, int BN, int AMODE, bool BIASRELU, bool DSCALE>
__global__ __launch_bounds__(512) void k_gemm4(const void* __restrict__ Ain,
                                               const unsigned short* __restrict__ Wt,
                                               const float* __restrict__ arena,
                                               const float* __restrict__ gamma,
                                               const float* __restrict__ beta,
                                               const float* __restrict__ svec,
                                               const float* __restrict__ bias,
                                               const float* __restrict__ dinv,
                                               unsigned short* __restrict__ Mout,
                                               int K, int NTOT) {
    constexpr int BK = 64;
    constexpr int LDA = 72;
    constexpr int AP = BM / 64;
    constexpr int BP = BN / 64;
    constexpr int MF = BM / 32;
    constexpr int NF = BN / 64;
    __shared__ unsigned short As[BM * LDA];
    __shared__ unsigned short Bs[BN * LDA];
    __shared__ float ss_sc[256];
    __shared__ float ss_sh[256];
    const int tid = threadIdx.x;
    const int lane = tid & 63;
    const int wv = tid >> 6;
    const int wm = wv >> 2;
    const int wn = wv & 3;
    const int row0 = blockIdx.x * BM;
    const int col0 = blockIdx.y * BN;

    if constexpr (AMODE >= 1) {
        for (int f = tid; f < K; f += 512) {
            float s1 = 0.f, s2 = 0.f;
#pragma unroll
            for (int s = 0; s < NSHADOW; ++s) {
                s1 += arena[s * 512 + f];
                s2 += arena[s * 512 + 256 + f];
            }
            float mean = s1 * (1.f / N_NODES);
            float var = s2 * (1.f / N_NODES) - mean * mean;
            float inv = rsqrtf(var + 1e-5f);
            float sc = gamma[f] * inv;
            ss_sc[f] = sc;
            ss_sh[f] = beta[f] - mean * sc;
        }
        __syncthreads();
    }

    const int sr = tid >> 3;
    const int scc = (tid & 7) * 8;

    float4 fa[AP][2];
    uint4 ua[AP];
    uint4 ub[BP];
    float sv[AP];

    auto LOAD = [&](int k0) {
#pragma unroll
        for (int p = 0; p < AP; ++p) {
            int gr = row0 + p * 64 + sr;
            if constexpr (AMODE == 0) {
                const float* Af = (const float*)Ain;
                fa[p][0] = make_float4(0.f, 0.f, 0.f, 0.f); fa[p][1] = fa[p][0];
                if (gr < N_NODES) {
                    const float* p0 = Af + (size_t)gr * K + k0 + scc;
                    fa[p][0] = *(const float4*)p0;
                    fa[p][1] = *(const float4*)(p0 + 4);
                }
            } else {
                const unsigned short* Ab = (const unsigned short*)Ain;
                ua[p] = make_uint4(0, 0, 0, 0);
                if (gr < N_NODES) ua[p] = *(const uint4*)(Ab + (size_t)gr * K + k0 + scc);
                if constexpr (AMODE == 2) sv[p] = (gr < N_NODES) ? svec[gr] : 0.f;
            }
        }
#pragma unroll
        for (int p = 0; p < BP; ++p)
            ub[p] = *(const uint4*)(Wt + (size_t)(col0 + p * 64 + sr) * K + k0 + scc);
    };

    auto WRITE = [&](int k0) {
#pragma unroll
        for (int p = 0; p < AP; ++p) {
            alignas(16) unsigned short tmp[8];
            if constexpr (AMODE == 0) {
                tmp[0] = f2bf(fa[p][0].x); tmp[1] = f2bf(fa[p][0].y);
                tmp[2] = f2bf(fa[p][0].z); tmp[3] = f2bf(fa[p][0].w);
                tmp[4] = f2bf(fa[p][1].x); tmp[5] = f2bf(fa[p][1].y);
                tmp[6] = f2bf(fa[p][1].z); tmp[7] = f2bf(fa[p][1].w);
            } else {
                const unsigned short* pr = (const unsigned short*)&ua[p];
#pragma unroll
                for (int q = 0; q < 8; ++q) {
                    float sc = ss_sc[k0 + scc + q];
                    float sh = ss_sh[k0 + scc + q];
                    float val;
                    if constexpr (AMODE == 2) val = bf2f(pr[q]) * sc + sh * sv[p];
                    else val = bf2f(pr[q]) * sc + sh;
                    tmp[q] = f2bf(val);
                }
            }
            *(uint4*)&As[(p * 64 + sr) * LDA + scc] = *(const uint4*)tmp;
        }
#pragma unroll
        for (int p = 0; p < BP; ++p) *(uint4*)&Bs[(p * 64 + sr) * LDA + scc] = ub[p];
    };

    f32x4 acc[MF][NF];
#pragma unroll
    for (int i = 0; i < MF; ++i)
#pragma unroll
        for (int j = 0; j < NF; ++j)
#pragma unroll
            for (int r = 0; r < 4; ++r) acc[i][j][r] = 0.f;

    LOAD(0);
    WRITE(0);
    __syncthreads();
    const int nk = K / BK;
    for (int kt = 1; kt <= nk; ++kt) {
        if (kt < nk) LOAD(kt * BK);
#pragma unroll
        for (int ks = 0; ks < 2; ++ks) {
            sh8 af[MF], bfr[NF];
#pragma unroll
            for (int i = 0; i < MF; ++i)
                af[i] = *(const sh8*)&As[(wm * (BM / 2) + i * 16 + (lane & 15)) * LDA + ks * 32 + (lane >> 4) * 8];
#pragma unroll
            for (int j = 0; j < NF; ++j)
                bfr[j] = *(const sh8*)&Bs[(wn * NF * 16 + j * 16 + (lane & 15)) * LDA + ks * 32 + (lane >> 4) * 8];
#pragma unroll
            for (int i = 0; i < MF; ++i)
#pragma unroll
                for (int j = 0; j < NF; ++j)
                    acc[i][j] = __builtin_amdgcn_mfma_f32_16x16x32_bf16(af[i], bfr[j], acc[i][j], 0, 0, 0);
        }
        __syncthreads();
        if (kt < nk) {
            WRITE(kt * BK);
            __syncthreads();
        }
    }

    // epilogue
#pragma unroll
    for (int i = 0; i < MF; ++i) {
#pragma unroll
        for (int r = 0; r < 4; ++r) {
            int grow = row0 + wm * (BM / 2) + i * 16 + (lane >> 4) * 4 + r;
            if (grow >= N_NODES) continue;
            float rsc = 1.f;
            if constexpr (DSCALE) rsc = dinv[grow];
#pragma unroll
            for (int j = 0; j < NF; ++j) {
                int gcol = col0 + wn * NF * 16 + j * 16 + (lane & 15);
                float v = acc[i][j][r];
                if constexpr (BIASRELU) v = fmaxf(v + bias[gcol], 0.f);
                if constexpr (DSCALE) v *= rsc;
                Mout[(size_t)grow * NTOT + gcol] = f2bf(v);
            }
        }
    }
}

// ---------------- layer-4 BN finalize+apply + classifier (wave per node) ----------------

__global__ __launch_bounds__(256) void k_bnlog(const float* __restrict__ out4, const float* __restrict__ sums,
                                               const float* __restrict__ gamma, const float* __restrict__ beta,
                                               const float* __restrict__ Wc, const float* __restrict__ bc,
                                               float* __restrict__ bn4, float* __restrict__ logits) {
    int gw = (blockIdx.x * 256 + threadIdx.x) >> 6;
    if (gw >= N_NODES) return;
    int f = threadIdx.x & 63;
    float mean = sums[f] * (1.f / N_NODES);
    float var = sums[256 + f] * (1.f / N_NODES) - mean * mean;
    float inv = rsqrtf(var + 1e-5f);
    float sc = gamma[f] * inv;
    float sh = beta[f] - mean * sc;
    float v = out4[(size_t)gw * 64 + f];
    float bn = v * sc + sh;
    bn4[(size_t)gw * 64 + f] = bn;
    float a0 = bn * Wc[2 * f];
    float a1 = bn * Wc[2 * f + 1];
#pragma unroll
    for (int off = 32; off; off >>= 1) {
        a0 += __shfl_down(a0, off, 64);
        a1 += __shfl_down(a1, off, 64);
    }
    if (f == 0) {
        logits[2 * gw] = a0 + bc[0];
        logits[2 * gw + 1] = a1 + bc[1];
    }
}

// ---------------- launch ----------------

extern "C" void kernel_launch(void* const* d_in, const int* in_sizes, int n_in,
                              void* d_out, int out_size, void* d_ws, size_t ws_size,
                              hipStream_t stream) {
    const float* x  = (const float*)d_in[0];
    const int* ei   = (const int*)d_in[1];
    const float* W1 = (const float*)d_in[2];  const float* b1  = (const float*)d_in[3];
    const float* W2 = (const float*)d_in[4];  const float* b2  = (const float*)d_in[5];
    const float* W3 = (const float*)d_in[6];  const float* b3  = (const float*)d_in[7];
    const float* W4 = (const float*)d_in[8];  const float* b4  = (const float*)d_in[9];
    const float* Wc = (const float*)d_in[10]; const float* bc  = (const float*)d_in[11];
    const float* g1 = (const float*)d_in[12]; const float* be1 = (const float*)d_in[13];
    const float* g2 = (const float*)d_in[14]; const float* be2 = (const float*)d_in[15];
    const float* g3 = (const float*)d_in[16]; const float* be3 = (const float*)d_in[17];
    const float* g4 = (const float*)d_in[18]; const float* be4 = (const float*)d_in[19];

    char* wsb = (char*)d_ws;
    size_t off = 0;
    auto alloc = [&](size_t bytes) -> void* {
        void* p = wsb + off;
        off = (off + bytes + 511) & ~(size_t)511;
        return p;
    };
    int* deg     = (int*)alloc((size_t)N_NODES * 4);
    int* basep   = (int*)alloc((size_t)N_NODES * 4);
    float* dinv  = (float*)alloc((size_t)N_NODES * 4);
    float* sdeg  = (float*)alloc((size_t)N_NODES * 4);
    float* svec  = (float*)alloc((size_t)N_NODES * 4);
    int* col     = (int*)alloc((size_t)N_EDGES * 4);
    unsigned* pairs = (unsigned*)alloc((size_t)N_EDGES * 4);
    int* histG   = (int*)alloc((size_t)NB * NBLK * 4);
    int* rowsum  = (int*)alloc((size_t)NB * 4);
    int* rowbase = (int*)alloc((size_t)(NB + 1) * 4);
    // sums4 (512 f32) + 4 shadow arenas (4 x 32 x 512 f32), contiguous, one memset
    float* sums4  = (float*)alloc(512 * 4);
    float* shadow = (float*)alloc((size_t)4 * NSHADOW * 512 * 4);
    unsigned short* Wt1 = (unsigned short*)alloc((size_t)256 * 128 * 2);
    unsigned short* Wt2 = (unsigned short*)alloc((size_t)128 * 256 * 2);
    unsigned short* Wt3 = (unsigned short*)alloc((size_t)256 * 128 * 2);
    unsigned short* Wt4 = (unsigned short*)alloc((size_t)128 * 64 * 2);
    unsigned short* mb = (unsigned short*)alloc((size_t)N_NODES * 128 * 2);
    unsigned short* hb = (unsigned short*)alloc((size_t)N_NODES * 256 * 2);

    float* arena1 = shadow;
    float* arena2 = shadow + NSHADOW * 512;
    float* arena3 = shadow + 2 * NSHADOW * 512;
    float* arena4 = shadow + 3 * NSHADOW * 512;

    float* outLogits = (float*)d_out;
    float* out4 = outLogits + (size_t)N_NODES * 2;
    float* bn4  = out4 + (size_t)N_NODES * 64;

    // single memset covers sums4 + all shadow arenas (contiguous, both 512B-aligned)
    hipMemsetAsync(sums4, 0, 512 * 4 + (size_t)4 * NSHADOW * 512 * 4, stream);

    // ---- CSR build: partition + bucket sort ----
    k_hist<<<NBLK, 256, 0, stream>>>(ei, histG);
    k_scanrow<<<NB, 128, 0, stream>>>(histG, rowsum);
    k_scanbkt<<<1, 512, 0, stream>>>(rowsum, rowbase);
    k_part<<<NBLK, 256, 0, stream>>>(ei, histG, rowbase, pairs);
    k_bsort<<<NB, 256, 0, stream>>>(pairs, rowbase, col, basep, deg, dinv, sdeg);
    k_wsvec<<<WCB + (N_NODES + 3) / 4, 256, 0, stream>>>(W1, W2, W3, W4, Wt1, Wt2, Wt3, Wt4,
                                                         col, basep, deg, dinv, svec);

    const int GB128 = (N_NODES + 127) / 128; // 782 row-tiles (BM=128)
    const int GB64  = (N_NODES + 63) / 64;   // 1563 row-tiles (BM=64)
    const int AB = (N_NODES + 3) / 4;        // 25000 blocks, wave per node
    const int HB = (N_NODES + 7) / 8;        // 12500 blocks, half-wave per node (D=64)

    // Layer 1: m1' = dinv*(x @ W1); agg -> q1 = dinv*h1 (bf16)
    k_gemm4<128, 128, 0, false, true><<<dim3(GB128, 1), 512, 0, stream>>>(
        x, Wt1, nullptr, nullptr, nullptr, nullptr, nullptr, dinv, mb, 256, 128);
    k_agg<128, false, false, true><<<AB, 256, 0, stream>>>(
        mb, col, basep, deg, dinv, b1, hb);

    // Fused: BN1 stats (arena1, on h1=q1*sdeg) || L2 PRE agg (A2 = di*(sum q1 + q1self))
    k_aggpre_stats<<<SB + AB, 256, 0, stream>>>(hb, col, basep, deg, dinv, sdeg, mb, arena1);

    // Layer 2: h2 = relu((sc1*A2 + sh1*svec) @ W2 + b2); BN2 stats (arena2)
    k_gemm4<128, 128, 2, true, false><<<dim3(GB128, 2), 512, 0, stream>>>(
        mb, Wt2, arena1, g1, be1, svec, b2, nullptr, hb, 128, 256);
    k_bnstats<256, false, false><<<SB, 256, 0, stream>>>(hb, nullptr, arena2);

    // Layer 3: m3' = dinv*(bn2(h2) @ W3); agg+b3+relu -> h3; BN3 stats (arena3)
    k_gemm4<128, 128, 1, false, true><<<dim3(GB128, 1), 512, 0, stream>>>(
        hb, Wt3, arena2, g2, be2, nullptr, nullptr, dinv, mb, 256, 128);
    k_agg<128, false, false, false><<<AB, 256, 0, stream>>>(
        mb, col, basep, deg, dinv, b3, hb);
    k_bnstats<128, false, false><<<SB, 256, 0, stream>>>(hb, nullptr, arena3);

    // Layer 4: m4' = dinv*(bn3(h3) @ W4); agg+b4+relu -> out4 (f32); BN4 stats (arena4); classifier
    k_gemm4<64, 64, 1, false, true><<<dim3(GB64, 1), 512, 0, stream>>>(
        hb, Wt4, arena3, g3, be3, nullptr, nullptr, dinv, mb, 128, 64);
    k_agg64<true><<<HB, 256, 0, stream>>>(
        mb, col, basep, deg, dinv, b4, out4);
    k_bnstats<64, true, false><<<SB, 256, 0, stream>>>(out4, nullptr, arena4);
    k_bnred<<<2, 256, 0, stream>>>(arena4, sums4);
    k_bnlog<<<(N_NODES * 64 + 255) / 256, 256, 0, stream>>>(out4, sums4, g4, be4, Wc, bc, bn4, outLogits);
}

// Round 15
// 581.740 us; speedup vs baseline: 1.1331x; 1.0110x over previous
//
#include <hip/hip_runtime.h>
#include <hip/hip_bf16.h>

#define N_NODES 100000
#define N_EDGES 1600000
#define NB ((N_NODES + 255) / 256)          // 391 dst-buckets of 256 nodes
#define CHUNK 16384
#define NBLK ((N_EDGES + CHUNK - 1) / CHUNK) // 98 partition blocks
#define NSHADOW 32
#define WCB 416                              // wconv blocks (106496 / 256)
#define SB 512                               // bnstats blocks

typedef short sh8 __attribute__((ext_vector_type(8)));
typedef float f32x4 __attribute__((ext_vector_type(4)));

__device__ __forceinline__ float bf2f(unsigned short s) {
    return __uint_as_float(((unsigned int)s) << 16);
}
__device__ __forceinline__ unsigned short f2bf(float f) {
    unsigned int u = __float_as_uint(f);
    unsigned int r = (u + 0x7FFFu + ((u >> 16) & 1u)) >> 16;
    return (unsigned short)r;
}
__device__ __forceinline__ float blo(unsigned int u) { return __uint_as_float(u << 16); }
__device__ __forceinline__ float bhi(unsigned int u) { return __uint_as_float(u & 0xffff0000u); }

// ---------------- fused: edge histogram (blocks [0,NBLK)) || W transpose+bf16 (blocks [NBLK, NBLK+WCB)) ----------------

__global__ __launch_bounds__(256) void k_hist_wconv(const int* __restrict__ ei, int* __restrict__ histG,
                                                    const float* __restrict__ W1, const float* __restrict__ W2,
                                                    const float* __restrict__ W3, const float* __restrict__ W4,
                                                    unsigned short* __restrict__ Wt1, unsigned short* __restrict__ Wt2,
                                                    unsigned short* __restrict__ Wt3, unsigned short* __restrict__ Wt4) {
    if (blockIdx.x < NBLK) {
        __shared__ int hist[NB];
        int blk = blockIdx.x, t = threadIdx.x;
        for (int b = t; b < NB; b += 256) hist[b] = 0;
        __syncthreads();
        int e0 = blk * CHUNK;
        int e1 = min(e0 + CHUNK, N_EDGES);
        for (int e = e0 + t; e < e1; e += 256) atomicAdd(&hist[ei[N_EDGES + e] >> 8], 1);
        __syncthreads();
        for (int b = t; b < NB; b += 256) histG[b * NBLK + blk] = hist[b];
        return;
    }
    int idx = (blockIdx.x - NBLK) * 256 + threadIdx.x;
    const float* W; unsigned short* Wt; int K, N, base;
    if (idx < 32768)       { W = W1; Wt = Wt1; K = 256; N = 128; base = 0; }
    else if (idx < 65536)  { W = W2; Wt = Wt2; K = 128; N = 256; base = 32768; }
    else if (idx < 98304)  { W = W3; Wt = Wt3; K = 256; N = 128; base = 65536; }
    else if (idx < 106496) { W = W4; Wt = Wt4; K = 128; N = 64;  base = 98304; }
    else return;
    int li = idx - base;
    int n = li / K, k = li - n * K;
    Wt[li] = f2bf(W[(size_t)k * N + n]);
}

__global__ __launch_bounds__(128) void k_scanrow(int* __restrict__ histG, int* __restrict__ rowsum) {
    __shared__ int sm[128];
    int b = blockIdx.x, t = threadIdx.x;
    int v = (t < NBLK) ? histG[b * NBLK + t] : 0;
    sm[t] = v; __syncthreads();
    for (int d = 1; d < 128; d <<= 1) {
        int add = (t >= d) ? sm[t - d] : 0;
        __syncthreads(); sm[t] += add; __syncthreads();
    }
    if (t < NBLK) histG[b * NBLK + t] = sm[t] - v;
    if (t == 127) rowsum[b] = sm[127];
}

__global__ __launch_bounds__(512) void k_scanbkt(const int* __restrict__ rowsum, int* __restrict__ rowbase) {
    __shared__ int sm[512];
    int t = threadIdx.x;
    int v = (t < NB) ? rowsum[t] : 0;
    sm[t] = v; __syncthreads();
    for (int d = 1; d < 512; d <<= 1) {
        int add = (t >= d) ? sm[t - d] : 0;
        __syncthreads(); sm[t] += add; __syncthreads();
    }
    if (t <= NB) rowbase[t] = sm[t] - v;
}

__global__ __launch_bounds__(256) void k_part(const int* __restrict__ ei, const int* __restrict__ histG,
                                              const int* __restrict__ rowbase, unsigned* __restrict__ pairs) {
    __shared__ int cur[NB];
    int blk = blockIdx.x, t = threadIdx.x;
    for (int b = t; b < NB; b += 256) cur[b] = rowbase[b] + histG[b * NBLK + blk];
    __syncthreads();
    int e0 = blk * CHUNK;
    int e1 = min(e0 + CHUNK, N_EDGES);
    for (int e = e0 + t; e < e1; e += 256) {
        int s = ei[e], d = ei[N_EDGES + e];
        int pos = atomicAdd(&cur[d >> 8], 1);
        pairs[pos] = ((unsigned)s << 8) | (unsigned)(d & 255);
    }
}

__global__ __launch_bounds__(256) void k_bsort(const unsigned* __restrict__ pairs, const int* __restrict__ rowbase,
                                               int* __restrict__ col, int* __restrict__ basep,
                                               int* __restrict__ deg, float* __restrict__ dinv,
                                               float* __restrict__ sdeg) {
    __shared__ int cnt[256];
    __shared__ int sm[256];
    __shared__ int cur[256];
    int b = blockIdx.x, t = threadIdx.x;
    int base = rowbase[b], end = rowbase[b + 1];
    cnt[t] = 0; __syncthreads();
    for (int e = base + t; e < end; e += 256) atomicAdd(&cnt[pairs[e] & 255], 1);
    __syncthreads();
    int v = cnt[t];
    sm[t] = v; __syncthreads();
    for (int d = 1; d < 256; d <<= 1) {
        int add = (t >= d) ? sm[t - d] : 0;
        __syncthreads(); sm[t] += add; __syncthreads();
    }
    int excl = sm[t] - v;
    cur[t] = excl;
    int gd = (b << 8) + t;
    if (gd < N_NODES) {
        basep[gd] = base + excl;
        deg[gd] = v;
        dinv[gd] = rsqrtf((float)(v + 1));
        sdeg[gd] = sqrtf((float)(v + 1));
    }
    __syncthreads();
    for (int e = base + t; e < end; e += 256) {
        unsigned p = pairs[e];
        int pos = atomicAdd(&cur[p & 255], 1);
        col[base + pos] = (int)(p >> 8);
    }
}

// ---------------- shadow reduce (layer 4 only): dst[f] = sum_s arena[s][f] ----------------

__global__ __launch_bounds__(256) void k_bnred(const float* __restrict__ arena, float* __restrict__ dst) {
    int f = blockIdx.x * 256 + threadIdx.x; // 0..511
    float s = 0.f;
#pragma unroll
    for (int i = 0; i < NSHADOW; ++i) s += arena[i * 512 + f];
    dst[f] = s;
}

// ---------------- BN stats body: arena += per-feature {sum, sumsq} ----------------

template <int D, bool INF32, bool RESCALE>
__device__ __forceinline__ void bnstats_body(int bid, int gridN, const void* __restrict__ h,
                                             const float* __restrict__ sdeg, float* __restrict__ arena) {
    constexpr int VEC = INF32 ? 4 : 8;
    constexpr int TPR = D / VEC;
    constexpr int RPB = 256 / TPR;
    const int tid = threadIdx.x;
    const int rg = tid / TPR;
    const int oc = tid % TPR;
    const int fb = oc * VEC;

    float s1[VEC], s2[VEC];
#pragma unroll
    for (int k = 0; k < VEC; ++k) { s1[k] = 0.f; s2[k] = 0.f; }

    for (int r = bid * RPB + rg; r < N_NODES; r += gridN * RPB) {
        float rs = 1.f;
        if constexpr (RESCALE) rs = sdeg[r];
        if constexpr (INF32) {
            float4 v = *(const float4*)((const float*)h + (size_t)r * D + fb);
            float vv[4] = {v.x, v.y, v.z, v.w};
#pragma unroll
            for (int k = 0; k < 4; ++k) {
                float val = vv[k];
                if constexpr (RESCALE) val *= rs;
                s1[k] += val; s2[k] += val * val;
            }
        } else {
            uint4 u = *(const uint4*)((const unsigned short*)h + (size_t)r * D + fb);
            unsigned uu[4] = {u.x, u.y, u.z, u.w};
#pragma unroll
            for (int k = 0; k < 4; ++k) {
                float v0 = blo(uu[k]), v1 = bhi(uu[k]);
                if constexpr (RESCALE) { v0 *= rs; v1 *= rs; }
                s1[2 * k] += v0;     s2[2 * k] += v0 * v0;
                s1[2 * k + 1] += v1; s2[2 * k + 1] += v1 * v1;
            }
        }
    }

    __shared__ float red[2][D];
    for (int i = tid; i < 2 * D; i += 256) ((float*)red)[i] = 0.f;
    __syncthreads();
#pragma unroll
    for (int k = 0; k < VEC; ++k) {
        atomicAdd(&red[0][fb + k], s1[k]);
        atomicAdd(&red[1][fb + k], s2[k]);
    }
    __syncthreads();
    float* slot = arena + ((bid & (NSHADOW - 1)) << 9);
    for (int i = tid; i < 2 * D; i += 256) {
        int f = (i < D) ? i : (256 + i - D);
        float v = (i < D) ? red[0][i] : red[1][i - D];
        atomicAdd(&slot[f], v);
    }
}

template <int D, bool INF32, bool RESCALE>
__global__ __launch_bounds__(256) void k_bnstats(const void* __restrict__ h,
                                                 const float* __restrict__ sdeg,
                                                 float* __restrict__ arena) {
    bnstats_body<D, INF32, RESCALE>(blockIdx.x, gridDim.x, h, sdeg, arena);
}

// ---------------- aggregation body (wave per node, unroll-8) ----------------

template <int D, bool PRE, bool OUTF32, bool OUTSCALE>
__device__ __forceinline__ void agg_body(int bid, const unsigned short* __restrict__ m,
                                         const int* __restrict__ col,
                                         const int* __restrict__ basep,
                                         const int* __restrict__ deg,
                                         const float* __restrict__ dinv,
                                         const float* __restrict__ bias,
                                         void* __restrict__ out) {
    constexpr int VPL = D / 64;
    const int w = (bid * 256 + threadIdx.x) >> 6;
    if (w >= N_NODES) return;
    const int lane = threadIdx.x & 63;
    const int fo = lane * VPL;
    const unsigned short* mfo = m + fo;
    float acc[VPL];
#pragma unroll
    for (int k = 0; k < VPL; ++k) acc[k] = 0.f;

    int start = basep[w], cnt = deg[w];
    int j = 0;
    for (; j + 8 <= cnt; j += 8) {
        int sx[8];
#pragma unroll
        for (int i = 0; i < 8; ++i) sx[i] = col[start + j + i];
        if constexpr (VPL == 2) {
            unsigned u[8];
#pragma unroll
            for (int i = 0; i < 8; ++i) u[i] = *(const unsigned*)(mfo + (size_t)sx[i] * D);
#pragma unroll
            for (int i = 0; i < 8; ++i) { acc[0] += blo(u[i]); acc[1] += bhi(u[i]); }
        } else {
            float v[8];
#pragma unroll
            for (int i = 0; i < 8; ++i) v[i] = bf2f(mfo[(size_t)sx[i] * D]);
#pragma unroll
            for (int i = 0; i < 8; ++i) acc[0] += v[i];
        }
    }
    for (; j < cnt; ++j) {
        int s0 = col[start + j];
        if constexpr (VPL == 2) {
            unsigned u0 = *(const unsigned*)(mfo + (size_t)s0 * D);
            acc[0] += blo(u0); acc[1] += bhi(u0);
        } else {
            acc[0] += bf2f(mfo[(size_t)s0 * D]);
        }
    }
    if constexpr (VPL == 2) {
        unsigned u0 = *(const unsigned*)(mfo + (size_t)w * D);
        acc[0] += blo(u0); acc[1] += bhi(u0);
    } else {
        acc[0] += bf2f(mfo[(size_t)w * D]);
    }

    float di = dinv[w];
    float o[VPL];
    if constexpr (PRE) {
#pragma unroll
        for (int k = 0; k < VPL; ++k) o[k] = acc[k] * di;
    } else {
#pragma unroll
        for (int k = 0; k < VPL; ++k) {
            o[k] = fmaxf(acc[k] * di + bias[fo + k], 0.f);
            if constexpr (OUTSCALE) o[k] *= di;
        }
    }

    if constexpr (OUTF32) {
        float* of = (float*)out;
#pragma unroll
        for (int k = 0; k < VPL; ++k) of[(size_t)w * D + fo + k] = o[k];
    } else {
        unsigned short* ob = (unsigned short*)out + (size_t)w * D + fo;
        if constexpr (VPL == 2) {
            unsigned int u = (unsigned)f2bf(o[0]) | ((unsigned)f2bf(o[1]) << 16);
            *(unsigned int*)ob = u;
        } else {
            ob[0] = f2bf(o[0]);
        }
    }
}

template <int D, bool PRE, bool OUTF32, bool OUTSCALE>
__global__ __launch_bounds__(256) void k_agg(const unsigned short* __restrict__ m,
                                             const int* __restrict__ col,
                                             const int* __restrict__ basep,
                                             const int* __restrict__ deg,
                                             const float* __restrict__ dinv,
                                             const float* __restrict__ bias,
                                             void* __restrict__ out) {
    agg_body<D, PRE, OUTF32, OUTSCALE>(blockIdx.x, m, col, basep, deg, dinv, bias, out);
}

// ---------------- fused: L1 POST agg (blocks [0,AB)) || svec (blocks [AB, ...)) ----------------

__global__ __launch_bounds__(256) void k_agg_svec(const unsigned short* __restrict__ m,
                                                  const int* __restrict__ col,
                                                  const int* __restrict__ basep,
                                                  const int* __restrict__ deg,
                                                  const float* __restrict__ dinv,
                                                  const float* __restrict__ bias,
                                                  unsigned short* __restrict__ out,
                                                  float* __restrict__ svec, int AB) {
    if (blockIdx.x < (unsigned)AB) {
        agg_body<128, false, false, true>(blockIdx.x, m, col, basep, deg, dinv, bias, out);
        return;
    }
    int sb = blockIdx.x - AB;
    int w = (sb * 256 + threadIdx.x) >> 6;
    if (w >= N_NODES) return;
    int lane = threadIdx.x & 63;
    int start = basep[w], cnt = deg[w];
    float s = 0.f;
    for (int j = lane; j < cnt; j += 64) s += dinv[col[start + j]];
#pragma unroll
    for (int off = 32; off; off >>= 1) s += __shfl_down(s, off, 64);
    if (lane == 0) { float di = dinv[w]; svec[w] = di * (s + di); }
}

// ---------------- fused: BN1 stats (blocks [0,SB)) || L2 PRE agg (blocks [SB, ...)) ----------------

__global__ __launch_bounds__(256) void k_aggpre_stats(const unsigned short* __restrict__ hb,
                                                      const int* __restrict__ col,
                                                      const int* __restrict__ basep,
                                                      const int* __restrict__ deg,
                                                      const float* __restrict__ dinv,
                                                      const float* __restrict__ sdeg,
                                                      unsigned short* __restrict__ mb,
                                                      float* __restrict__ arena) {
    if (blockIdx.x < SB) {
        bnstats_body<128, false, true>(blockIdx.x, SB, hb, sdeg, arena);
    } else {
        agg_body<128, true, false, false>(blockIdx.x - SB, hb, col, basep, deg, dinv, nullptr, mb);
    }
}

// ---------------- D=64 aggregation: half-wave per node, 4B loads ----------------

template <bool OUTF32>
__global__ __launch_bounds__(256) void k_agg64(const unsigned short* __restrict__ m,
                                               const int* __restrict__ col,
                                               const int* __restrict__ basep,
                                               const int* __restrict__ deg,
                                               const float* __restrict__ dinv,
                                               const float* __restrict__ bias,
                                               void* __restrict__ out) {
    const int w = (blockIdx.x * 256 + threadIdx.x) >> 5;  // node per half-wave
    if (w >= N_NODES) return;
    const int hl = threadIdx.x & 31;
    const int fo = hl * 2;
    const unsigned short* mfo = m + fo;
    float acc0 = 0.f, acc1 = 0.f;

    int start = basep[w], cnt = deg[w];
    int j = 0;
    for (; j + 8 <= cnt; j += 8) {
        int sx[8];
#pragma unroll
        for (int i = 0; i < 8; ++i) sx[i] = col[start + j + i];
        unsigned u[8];
#pragma unroll
        for (int i = 0; i < 8; ++i) u[i] = *(const unsigned*)(mfo + (size_t)sx[i] * 64);
#pragma unroll
        for (int i = 0; i < 8; ++i) { acc0 += blo(u[i]); acc1 += bhi(u[i]); }
    }
    for (; j < cnt; ++j) {
        int s0 = col[start + j];
        unsigned u0 = *(const unsigned*)(mfo + (size_t)s0 * 64);
        acc0 += blo(u0); acc1 += bhi(u0);
    }
    {
        unsigned u0 = *(const unsigned*)(mfo + (size_t)w * 64);
        acc0 += blo(u0); acc1 += bhi(u0);
    }

    float di = dinv[w];
    float o0 = fmaxf(acc0 * di + bias[fo], 0.f);
    float o1 = fmaxf(acc1 * di + bias[fo + 1], 0.f);

    if constexpr (OUTF32) {
        *(float2*)((float*)out + (size_t)w * 64 + fo) = make_float2(o0, o1);
    } else {
        unsigned u = (unsigned)f2bf(o0) | ((unsigned)f2bf(o1) << 16);
        *(unsigned*)((unsigned short*)out + (size_t)w * 64 + fo) = u;
    }
}

// ---------------- pipelined bf16 MFMA GEMM (512 threads, BMxBN tiles, register prefetch) ----------------
// AMODE: 0=f32 plain; 1=bf16, A'=sc[k]*A+sh[k] (sc/sh from 32-slot shadow arena + gamma/beta);
//        2=same + sh[k]*svec[row]
// BIASRELU: out=relu(acc+bias[col]); DSCALE: out *= dinv[row]; STATS: fused BN sums -> arena_out

template <int BM, int BN, int AMODE, bool BIASRELU, bool DSCALE, bool STATS>
__global__ __launch_bounds__(512) void k_gemm4(const void* __restrict__ Ain,
                                               const unsigned short* __restrict__ Wt,
                                               const float* __restrict__ arena,
                                               const float* __restrict__ gamma,
                                               const float* __restrict__ beta,
                                               const float* __restrict__ svec,
                                               const float* __restrict__ bias,
                                               const float* __restrict__ dinv,
                                               unsigned short* __restrict__ Mout,
                                               float* __restrict__ arena_out,
                                               int K, int NTOT) {
    constexpr int BK = 64;
    constexpr int LDA = 72;
    constexpr int AP = BM / 64;
    constexpr int BP = BN / 64;
    constexpr int MF = BM / 32;
    constexpr int NF = BN / 64;
    __shared__ unsigned short As[BM * LDA];
    __shared__ unsigned short Bs[BN * LDA];
    __shared__ float ss_sc[256];
    __shared__ float ss_sh[256];
    const int tid = threadIdx.x;
    const int lane = tid & 63;
    const int wv = tid >> 6;
    const int wm = wv >> 2;
    const int wn = wv & 3;
    const int row0 = blockIdx.x * BM;
    const int col0 = blockIdx.y * BN;

    if constexpr (AMODE >= 1) {
        for (int f = tid; f < K; f += 512) {
            float s1 = 0.f, s2 = 0.f;
#pragma unroll
            for (int s = 0; s < NSHADOW; ++s) {
                s1 += arena[s * 512 + f];
                s2 += arena[s * 512 + 256 + f];
            }
            float mean = s1 * (1.f / N_NODES);
            float var = s2 * (1.f / N_NODES) - mean * mean;
            float inv = rsqrtf(var + 1e-5f);
            float sc = gamma[f] * inv;
            ss_sc[f] = sc;
            ss_sh[f] = beta[f] - mean * sc;
        }
        __syncthreads();
    }

    const int sr = tid >> 3;
    const int scc = (tid & 7) * 8;

    float4 fa[AP][2];
    uint4 ua[AP];
    uint4 ub[BP];
    float sv[AP];

    auto LOAD = [&](int k0) {
#pragma unroll
        for (int p = 0; p < AP; ++p) {
            int gr = row0 + p * 64 + sr;
            if constexpr (AMODE == 0) {
                const float* Af = (const float*)Ain;
                fa[p][0] = make_float4(0.f, 0.f, 0.f, 0.f); fa[p][1] = fa[p][0];
                if (gr < N_NODES) {
                    const float* p0 = Af + (size_t)gr * K + k0 + scc;
                    fa[p][0] = *(const float4*)p0;
                    fa[p][1] = *(const float4*)(p0 + 4);
                }
            } else {
                const unsigned short* Ab = (const unsigned short*)Ain;
                ua[p] = make_uint4(0, 0, 0, 0);
                if (gr < N_NODES) ua[p] = *(const uint4*)(Ab + (size_t)gr * K + k0 + scc);
                if constexpr (AMODE == 2) sv[p] = (gr < N_NODES) ? svec[gr] : 0.f;
            }
        }
#pragma unroll
        for (int p = 0; p < BP; ++p)
            ub[p] = *(const uint4*)(Wt + (size_t)(col0 + p * 64 + sr) * K + k0 + scc);
    };

    auto WRITE = [&](int k0) {
#pragma unroll
        for (int p = 0; p < AP; ++p) {
            alignas(16) unsigned short tmp[8];
            if constexpr (AMODE == 0) {
                tmp[0] = f2bf(fa[p][0].x); tmp[1] = f2bf(fa[p][0].y);
                tmp[2] = f2bf(fa[p][0].z); tmp[3] = f2bf(fa[p][0].w);
                tmp[4] = f2bf(fa[p][1].x); tmp[5] = f2bf(fa[p][1].y);
                tmp[6] = f2bf(fa[p][1].z); tmp[7] = f2bf(fa[p][1].w);
            } else {
                const unsigned short* pr = (const unsigned short*)&ua[p];
#pragma unroll
                for (int q = 0; q < 8; ++q) {
                    float sc = ss_sc[k0 + scc + q];
                    float sh = ss_sh[k0 + scc + q];
                    float val;
                    if constexpr (AMODE == 2) val = bf2f(pr[q]) * sc + sh * sv[p];
                    else val = bf2f(pr[q]) * sc + sh;
                    tmp[q] = f2bf(val);
                }
            }
            *(uint4*)&As[(p * 64 + sr) * LDA + scc] = *(const uint4*)tmp;
        }
#pragma unroll
        for (int p = 0; p < BP; ++p) *(uint4*)&Bs[(p * 64 + sr) * LDA + scc] = ub[p];
    };

    f32x4 acc[MF][NF];
#pragma unroll
    for (int i = 0; i < MF; ++i)
#pragma unroll
        for (int j = 0; j < NF; ++j)
#pragma unroll
            for (int r = 0; r < 4; ++r) acc[i][j][r] = 0.f;

    LOAD(0);
    WRITE(0);
    __syncthreads();
    const int nk = K / BK;
    for (int kt = 1; kt <= nk; ++kt) {
        if (kt < nk) LOAD(kt * BK);
#pragma unroll
        for (int ks = 0; ks < 2; ++ks) {
            sh8 af[MF], bfr[NF];
#pragma unroll
            for (int i = 0; i < MF; ++i)
                af[i] = *(const sh8*)&As[(wm * (BM / 2) + i * 16 + (lane & 15)) * LDA + ks * 32 + (lane >> 4) * 8];
#pragma unroll
            for (int j = 0; j < NF; ++j)
                bfr[j] = *(const sh8*)&Bs[(wn * NF * 16 + j * 16 + (lane & 15)) * LDA + ks * 32 + (lane >> 4) * 8];
#pragma unroll
            for (int i = 0; i < MF; ++i)
#pragma unroll
                for (int j = 0; j < NF; ++j)
                    acc[i][j] = __builtin_amdgcn_mfma_f32_16x16x32_bf16(af[i], bfr[j], acc[i][j], 0, 0, 0);
        }
        __syncthreads();
        if (kt < nk) {
            WRITE(kt * BK);
            __syncthreads();
        }
    }

    // epilogue (+ optional fused BN stats)
    float cs[NF], cs2[NF];
    if constexpr (STATS) {
#pragma unroll
        for (int j = 0; j < NF; ++j) { cs[j] = 0.f; cs2[j] = 0.f; }
    }
#pragma unroll
    for (int i = 0; i < MF; ++i) {
#pragma unroll
        for (int r = 0; r < 4; ++r) {
            int grow = row0 + wm * (BM / 2) + i * 16 + (lane >> 4) * 4 + r;
            if (grow >= N_NODES) continue;
            float rsc = 1.f;
            if constexpr (DSCALE) rsc = dinv[grow];
#pragma unroll
            for (int j = 0; j < NF; ++j) {
                int gcol = col0 + wn * NF * 16 + j * 16 + (lane & 15);
                float v = acc[i][j][r];
                if constexpr (BIASRELU) v = fmaxf(v + bias[gcol], 0.f);
                if constexpr (DSCALE) v *= rsc;
                if constexpr (STATS) { cs[j] += v; cs2[j] += v * v; }
                Mout[(size_t)grow * NTOT + gcol] = f2bf(v);
            }
        }
    }
    if constexpr (STATS) {
        __shared__ float red[2][BN];
        for (int i = tid; i < 2 * BN; i += 512) ((float*)red)[i] = 0.f;
        __syncthreads();
#pragma unroll
        for (int j = 0; j < NF; ++j) {
            int lc = wn * NF * 16 + j * 16 + (lane & 15);
            atomicAdd(&red[0][lc], cs[j]);
            atomicAdd(&red[1][lc], cs2[j]);
        }
        __syncthreads();
        float* slot = arena_out + ((blockIdx.x & (NSHADOW - 1)) << 9);
        for (int f = tid; f < BN; f += 512) {
            atomicAdd(&slot[col0 + f], red[0][f]);
            atomicAdd(&slot[256 + col0 + f], red[1][f]);
        }
    }
}

// ---------------- layer-4 BN finalize+apply + classifier (wave per node) ----------------

__global__ __launch_bounds__(256) void k_bnlog(const float* __restrict__ out4, const float* __restrict__ sums,
                                               const float* __restrict__ gamma, const float* __restrict__ beta,
                                               const float* __restrict__ Wc, const float* __restrict__ bc,
                                               float* __restrict__ bn4, float* __restrict__ logits) {
    int gw = (blockIdx.x * 256 + threadIdx.x) >> 6;
    if (gw >= N_NODES) return;
    int f = threadIdx.x & 63;
    float mean = sums[f] * (1.f / N_NODES);
    float var = sums[256 + f] * (1.f / N_NODES) - mean * mean;
    float inv = rsqrtf(var + 1e-5f);
    float sc = gamma[f] * inv;
    float sh = beta[f] - mean * sc;
    float v = out4[(size_t)gw * 64 + f];
    float bn = v * sc + sh;
    bn4[(size_t)gw * 64 + f] = bn;
    float a0 = bn * Wc[2 * f];
    float a1 = bn * Wc[2 * f + 1];
#pragma unroll
    for (int off = 32; off; off >>= 1) {
        a0 += __shfl_down(a0, off, 64);
        a1 += __shfl_down(a1, off, 64);
    }
    if (f == 0) {
        logits[2 * gw] = a0 + bc[0];
        logits[2 * gw + 1] = a1 + bc[1];
    }
}

// ---------------- launch ----------------

extern "C" void kernel_launch(void* const* d_in, const int* in_sizes, int n_in,
                              void* d_out, int out_size, void* d_ws, size_t ws_size,
                              hipStream_t stream) {
    const float* x  = (const float*)d_in[0];
    const int* ei   = (const int*)d_in[1];
    const float* W1 = (const float*)d_in[2];  const float* b1  = (const float*)d_in[3];
    const float* W2 = (const float*)d_in[4];  const float* b2  = (const float*)d_in[5];
    const float* W3 = (const float*)d_in[6];  const float* b3  = (const float*)d_in[7];
    const float* W4 = (const float*)d_in[8];  const float* b4  = (const float*)d_in[9];
    const float* Wc = (const float*)d_in[10]; const float* bc  = (const float*)d_in[11];
    const float* g1 = (const float*)d_in[12]; const float* be1 = (const float*)d_in[13];
    const float* g2 = (const float*)d_in[14]; const float* be2 = (const float*)d_in[15];
    const float* g3 = (const float*)d_in[16]; const float* be3 = (const float*)d_in[17];
    const float* g4 = (const float*)d_in[18]; const float* be4 = (const float*)d_in[19];

    char* wsb = (char*)d_ws;
    size_t off = 0;
    auto alloc = [&](size_t bytes) -> void* {
        void* p = wsb + off;
        off = (off + bytes + 511) & ~(size_t)511;
        return p;
    };
    int* deg     = (int*)alloc((size_t)N_NODES * 4);
    int* basep   = (int*)alloc((size_t)N_NODES * 4);
    float* dinv  = (float*)alloc((size_t)N_NODES * 4);
    float* sdeg  = (float*)alloc((size_t)N_NODES * 4);
    float* svec  = (float*)alloc((size_t)N_NODES * 4);
    int* col     = (int*)alloc((size_t)N_EDGES * 4);
    unsigned* pairs = (unsigned*)alloc((size_t)N_EDGES * 4);
    int* histG   = (int*)alloc((size_t)NB * NBLK * 4);
    int* rowsum  = (int*)alloc((size_t)NB * 4);
    int* rowbase = (int*)alloc((size_t)(NB + 1) * 4);
    // sums4 (512 f32) + 4 shadow arenas (4 x 32 x 512 f32), contiguous, one memset
    float* sums4  = (float*)alloc(512 * 4);
    float* shadow = (float*)alloc((size_t)4 * NSHADOW * 512 * 4);
    unsigned short* Wt1 = (unsigned short*)alloc((size_t)256 * 128 * 2);
    unsigned short* Wt2 = (unsigned short*)alloc((size_t)128 * 256 * 2);
    unsigned short* Wt3 = (unsigned short*)alloc((size_t)256 * 128 * 2);
    unsigned short* Wt4 = (unsigned short*)alloc((size_t)128 * 64 * 2);
    unsigned short* mb = (unsigned short*)alloc((size_t)N_NODES * 128 * 2);
    unsigned short* hb = (unsigned short*)alloc((size_t)N_NODES * 256 * 2);

    float* arena1 = shadow;
    float* arena2 = shadow + NSHADOW * 512;
    float* arena3 = shadow + 2 * NSHADOW * 512;
    float* arena4 = shadow + 3 * NSHADOW * 512;

    float* outLogits = (float*)d_out;
    float* out4 = outLogits + (size_t)N_NODES * 2;
    float* bn4  = out4 + (size_t)N_NODES * 64;

    hipMemsetAsync(sums4, 0, 512 * 4 + (size_t)4 * NSHADOW * 512 * 4, stream);

    // ---- CSR build (+ W conversion fused into hist dispatch) ----
    k_hist_wconv<<<NBLK + WCB, 256, 0, stream>>>(ei, histG, W1, W2, W3, W4, Wt1, Wt2, Wt3, Wt4);
    k_scanrow<<<NB, 128, 0, stream>>>(histG, rowsum);
    k_scanbkt<<<1, 512, 0, stream>>>(rowsum, rowbase);
    k_part<<<NBLK, 256, 0, stream>>>(ei, histG, rowbase, pairs);
    k_bsort<<<NB, 256, 0, stream>>>(pairs, rowbase, col, basep, deg, dinv, sdeg);

    const int GB128 = (N_NODES + 127) / 128; // 782 row-tiles (BM=128)
    const int GB64  = (N_NODES + 63) / 64;   // 1563 row-tiles (BM=64)
    const int AB = (N_NODES + 3) / 4;        // 25000 blocks, wave per node
    const int HB = (N_NODES + 7) / 8;        // 12500 blocks, half-wave per node (D=64)

    // Layer 1: m1' = dinv*(x @ W1); fused: agg -> q1 = dinv*h1 (bf16) || svec
    k_gemm4<128, 128, 0, false, true, false><<<dim3(GB128, 1), 512, 0, stream>>>(
        x, Wt1, nullptr, nullptr, nullptr, nullptr, nullptr, dinv, mb, nullptr, 256, 128);
    k_agg_svec<<<AB + AB, 256, 0, stream>>>(
        mb, col, basep, deg, dinv, b1, hb, svec, AB);

    // Fused: BN1 stats (arena1, on h1=q1*sdeg) || L2 PRE agg (A2 = di*(sum q1 + q1self))
    k_aggpre_stats<<<SB + AB, 256, 0, stream>>>(hb, col, basep, deg, dinv, sdeg, mb, arena1);

    // Layer 2: h2 = relu((sc1*A2 + sh1*svec) @ W2 + b2) + fused BN2 stats (arena2)
    k_gemm4<128, 128, 2, true, false, true><<<dim3(GB128, 2), 512, 0, stream>>>(
        mb, Wt2, arena1, g1, be1, svec, b2, nullptr, hb, arena2, 128, 256);

    // Layer 3: m3' = dinv*(bn2(h2) @ W3); agg+b3+relu -> h3; BN3 stats (arena3)
    k_gemm4<128, 128, 1, false, true, false><<<dim3(GB128, 1), 512, 0, stream>>>(
        hb, Wt3, arena2, g2, be2, nullptr, nullptr, dinv, mb, nullptr, 256, 128);
    k_agg<128, false, false, false><<<AB, 256, 0, stream>>>(
        mb, col, basep, deg, dinv, b3, hb);
    k_bnstats<128, false, false><<<SB, 256, 0, stream>>>(hb, nullptr, arena3);

    // Layer 4: m4' = dinv*(bn3(h3) @ W4); agg+b4+relu -> out4 (f32); BN4 stats (arena4); classifier
    k_gemm4<64, 64, 1, false, true, false><<<dim3(GB64, 1), 512, 0, stream>>>(
        hb, Wt4, arena3, g3, be3, nullptr, nullptr, dinv, mb, nullptr, 128, 64);
    k_agg64<true><<<HB, 256, 0, stream>>>(
        mb, col, basep, deg, dinv, b4, out4);
    k_bnstats<64, true, false><<<SB, 256, 0, stream>>>(out4, nullptr, arena4);
    k_bnred<<<2, 256, 0, stream>>>(arena4, sums4);
    k_bnlog<<<(N_NODES * 64 + 255) / 256, 256, 0, stream>>>(out4, sums4, g4, be4, Wc, bc, bn4, outLogits);
}